// Round 1
// 190.609 us; speedup vs baseline: 1.0952x; 1.0952x over previous
//
#include <hip/hip_runtime.h>
#include <hip/hip_bf16.h>

typedef __bf16 bf16_t;
typedef __bf16 bf16x8 __attribute__((ext_vector_type(8)));
typedef __bf16 bf16x4 __attribute__((ext_vector_type(4)));
typedef float  f32x4  __attribute__((ext_vector_type(4)));

#define MFMA16(a, b, c) __builtin_amdgcn_mfma_f32_16x16x32_bf16((a), (b), (c), 0, 0, 0)

constexpr int E  = 1024;
constexpr int S  = 2048;
constexpr int H  = 16;
constexpr int M  = 4096;  // B*S

// ---------------------------------------------------------------------------
// async global->LDS 16B (wave-uniform LDS base + lane*16)
// ---------------------------------------------------------------------------
__device__ __forceinline__ void glds16(const bf16_t* src, bf16_t* dst) {
  __builtin_amdgcn_global_load_lds(
      (const __attribute__((address_space(1))) void*)src,
      (__attribute__((address_space(3))) void*)dst, 16, 0, 0);
}

// Stage a [ROWS x 64] bf16 tile (global row stride gld) into LDS, XOR-swizzled.
template <int ROWS, int NT>
__device__ __forceinline__ void stage_tile(const bf16_t* g, int gld,
                                           bf16_t* lds, int tid) {
  const int w = tid >> 6, l = tid & 63;
#pragma unroll
  for (int i = 0; i < ROWS * 8 / NT; ++i) {
    const int c = i * NT + w * 64 + l;
    const int row = c >> 3;
    const int gch = (c & 7) ^ (row & 7);
    glds16(g + (size_t)row * gld + gch * 8, lds + (size_t)(i * NT + w * 64) * 8);
  }
}

// Read an 8-elem k-chunk (kc in [0,8)) of row `row` from a swizzled tile.
__device__ __forceinline__ bf16x8 read_frag(const bf16_t* lds, int row, int kc) {
  return *(const bf16x8*)(lds + (size_t)((row << 3) + (kc ^ (row & 7))) * 8);
}

// ---------------------------------------------------------------------------
// fused fp32->bf16 conversion for x + 4 weight matrices
// ---------------------------------------------------------------------------
__global__ void cvt_all_kernel(const float* __restrict__ x,
                               const float* __restrict__ w0, const float* __restrict__ w1,
                               const float* __restrict__ w2, const float* __restrict__ w3,
                               bf16_t* __restrict__ xb,
                               bf16_t* __restrict__ o0, bf16_t* __restrict__ o1,
                               bf16_t* __restrict__ o2, bf16_t* __restrict__ o3) {
  const int bid = blockIdx.x;
  const float* s;
  bf16_t* d;
  int idx;
  if (bid < 4096) {
    s = x; d = xb; idx = bid * 256 + threadIdx.x;
  } else {
    const int seg = (bid - 4096) >> 10;
    s = seg == 0 ? w0 : seg == 1 ? w1 : seg == 2 ? w2 : w3;
    d = seg == 0 ? o0 : seg == 1 ? o1 : seg == 2 ? o2 : o3;
    idx = ((bid - 4096) & 1023) * 256 + threadIdx.x;
  }
  float4 v = ((const float4*)s)[idx];
  bf16x4 o;
  o[0] = (bf16_t)v.x; o[1] = (bf16_t)v.y; o[2] = (bf16_t)v.z; o[3] = (bf16_t)v.w;
  ((bf16x4*)d)[idx] = o;
}

// ---------------------------------------------------------------------------
// m97-style GEMM core: 128x128 tile, BK=64, global_load_lds staging.
// ---------------------------------------------------------------------------
__device__ __forceinline__ void gemm_core(const bf16_t* __restrict__ A,
                                          const bf16_t* __restrict__ W, int Kd,
                                          bf16_t* As, bf16_t* Bs, int tid,
                                          f32x4 acc[4][4]) {
  const int w = tid >> 6, l = tid & 63;
  const int lq = l & 15, qd = l >> 4;
  const int wr = (w >> 1) * 64, wc = (w & 1) * 64;
#pragma unroll
  for (int i = 0; i < 4; ++i)
#pragma unroll
    for (int j = 0; j < 4; ++j) acc[i][j] = (f32x4){0.f, 0.f, 0.f, 0.f};

  const int KT = Kd / 64;
  for (int kt = 0; kt < KT; ++kt) {
    __syncthreads();
    stage_tile<128, 256>(A + kt * 64, Kd, As, tid);
    stage_tile<128, 256>(W + kt * 64, Kd, Bs, tid);
    __syncthreads();
#pragma unroll
    for (int ks = 0; ks < 2; ++ks) {
      bf16x8 af[4], bw[4];
#pragma unroll
      for (int mi = 0; mi < 4; ++mi)
        af[mi] = read_frag(As, wr + mi * 16 + lq, ks * 4 + qd);
#pragma unroll
      for (int ni = 0; ni < 4; ++ni)
        bw[ni] = read_frag(Bs, wc + ni * 16 + lq, ks * 4 + qd);
#pragma unroll
      for (int mi = 0; mi < 4; ++mi)
#pragma unroll
        for (int ni = 0; ni < 4; ++ni)
          acc[mi][ni] = MFMA16(af[mi], bw[ni], acc[mi][ni]);
    }
  }
}

// ---------------------------------------------------------------------------
// fused QKV projection. grid (24, 32). All outputs row-major [4096,1024] bf16.
// Q PRE-SCALED by log2(e)/sqrt(Dh) (folds softmax scale).
// ---------------------------------------------------------------------------
__global__ __launch_bounds__(256) void qkv_gemm_kernel(
    const bf16_t* __restrict__ xb,
    const bf16_t* __restrict__ wq, const bf16_t* __restrict__ wk,
    const bf16_t* __restrict__ wv,
    const float* __restrict__ bq, const float* __restrict__ bk,
    const float* __restrict__ bv,
    bf16_t* __restrict__ Qb, bf16_t* __restrict__ Kb, bf16_t* __restrict__ Vb) {
  __shared__ __align__(16) bf16_t As[128 * 64];
  __shared__ __align__(16) bf16_t Bs[128 * 64];
  const int tid = threadIdx.x;
  const int which = blockIdx.x >> 3;
  const int n0 = (blockIdx.x & 7) * 128;
  const int m0 = blockIdx.y * 128;
  const bf16_t* Wp = which == 0 ? wq : which == 1 ? wk : wv;
  const float* bp  = which == 0 ? bq : which == 1 ? bk : bv;
  bf16_t* Out      = which == 0 ? Qb : which == 1 ? Kb : Vb;
  const float sc = (which == 0) ? (1.4426950408889634f * 0.125f) : 1.0f;

  f32x4 acc[4][4];
  gemm_core(xb + (size_t)m0 * E, Wp + (size_t)n0 * E, E, As, Bs, tid, acc);

  const int w = tid >> 6, l = tid & 63, lq = l & 15, qd = l >> 4;
  const int wr = (w >> 1) * 64, wc = (w & 1) * 64;
#pragma unroll
  for (int ni = 0; ni < 4; ++ni) {
    const int col = n0 + wc + ni * 16 + lq;
    const float bvv = bp[col];
#pragma unroll
    for (int mi = 0; mi < 4; ++mi)
#pragma unroll
      for (int r = 0; r < 4; ++r) {
        const int row = m0 + wr + mi * 16 + qd * 4 + r;
        Out[(size_t)row * E + col] = (bf16_t)((acc[mi][ni][r] + bvv) * sc);
      }
  }
}

// ---------------------------------------------------------------------------
// V transpose: Vb [4096,1024] -> VT[bh][d][s], keys sigma-permuted per 64:
// VT[bh][d][64*blk + p] = V[64*blk + sigma(p)][d],
// sigma(p) = ((p>>5)*2 + ((p&7)>>2))*16 + ((p>>3)&3)*4 + (p&3)
// (chosen so that the attn kernel's S^T accumulator registers are directly
// the PV A-fragment; inverse: sl = a*16+b*4+c -> p = (a>>1)*32+b*8+(a&1)*4+c).
// ---------------------------------------------------------------------------
__global__ __launch_bounds__(256) void vtrans_kernel(const bf16_t* __restrict__ Vb,
                                                     bf16_t* __restrict__ VT) {
  constexpr int LDT = 72;
  __shared__ __align__(16) bf16_t T[64 * LDT];  // T[p][d] = V[s0+sigma(p)][d]
  const int tid = threadIdx.x;
  const int st = blockIdx.x, bh = blockIdx.y;
  const int b = bh >> 4, h = bh & 15;
  const int s0 = st * 64;
  const size_t rowbase = (size_t)b * S;
#pragma unroll
  for (int i = 0; i < 2; ++i) {
    const int c = i * 256 + tid;
    const int sl = c >> 3, dp = c & 7;
    const int a = sl >> 4, bb = (sl >> 2) & 3, cc = sl & 3;
    const int p = (a >> 1) * 32 + bb * 8 + (a & 1) * 4 + cc;  // sigma^-1(sl)
    bf16x8 v = *(const bf16x8*)(Vb + (rowbase + s0 + sl) * E + h * 64 + dp * 8);
    *(bf16x8*)&T[p * LDT + dp * 8] = v;
  }
  __syncthreads();
#pragma unroll
  for (int i = 0; i < 2; ++i) {
    const int c = i * 256 + tid;
    const int d = c >> 3, pp = (c & 7) * 8;
    bf16x8 o;
#pragma unroll
    for (int j = 0; j < 8; ++j) o[j] = T[(pp + j) * LDT + d];
    *(bf16x8*)&VT[((size_t)bh * 64 + d) * S + s0 + pp] = o;
  }
}

// ---------------------------------------------------------------------------
// output projection: 64x128 tiles -> grid (8, 64) = 512 blocks.
// ---------------------------------------------------------------------------
__global__ __launch_bounds__(256) void oproj_gemm_kernel(
    const bf16_t* __restrict__ Ob, const bf16_t* __restrict__ wo,
    const float* __restrict__ bo, float* __restrict__ out) {
  __shared__ __align__(16) bf16_t As[64 * 64];    // 8 KB
  __shared__ __align__(16) bf16_t Bs[128 * 64];   // 16 KB
  const int tid = threadIdx.x;
  const int n0 = blockIdx.x * 128;
  const int m0 = blockIdx.y * 64;
  const int w = tid >> 6, l = tid & 63, lq = l & 15, qd = l >> 4;
  const int wr = (w >> 1) * 32, wc = (w & 1) * 64;

  f32x4 acc[2][4];
#pragma unroll
  for (int i = 0; i < 2; ++i)
#pragma unroll
    for (int j = 0; j < 4; ++j) acc[i][j] = (f32x4){0.f, 0.f, 0.f, 0.f};

  for (int kt = 0; kt < 16; ++kt) {
    __syncthreads();
    stage_tile<64, 256>(Ob + (size_t)m0 * E + kt * 64, E, As, tid);
    stage_tile<128, 256>(wo + (size_t)n0 * E + kt * 64, E, Bs, tid);
    __syncthreads();
#pragma unroll
    for (int ks = 0; ks < 2; ++ks) {
      bf16x8 af[2], bw[4];
#pragma unroll
      for (int mi = 0; mi < 2; ++mi)
        af[mi] = read_frag(As, wr + mi * 16 + lq, ks * 4 + qd);
#pragma unroll
      for (int ni = 0; ni < 4; ++ni)
        bw[ni] = read_frag(Bs, wc + ni * 16 + lq, ks * 4 + qd);
#pragma unroll
      for (int mi = 0; mi < 2; ++mi)
#pragma unroll
        for (int ni = 0; ni < 4; ++ni)
          acc[mi][ni] = MFMA16(af[mi], bw[ni], acc[mi][ni]);
    }
  }
#pragma unroll
  for (int ni = 0; ni < 4; ++ni) {
    const int col = n0 + wc + ni * 16 + lq;
    const float bvv = bo[col];
#pragma unroll
    for (int mi = 0; mi < 2; ++mi)
#pragma unroll
      for (int r = 0; r < 4; ++r) {
        const int row = m0 + wr + mi * 16 + qd * 4 + r;
        out[(size_t)row * E + col] = acc[mi][ni][r] + bvv;
      }
  }
}

// ---------------------------------------------------------------------------
// causal flash attention v12: operand-swapped S^T = K*Q^T (softmax'd regs ARE
// the PV A-fragment; keys sigma-permuted in VT; P never touches LDS).
//
// v12 changes vs v11 (65 us, MfmaUtil 10%, Occupancy 11.3% = decaying tail):
//  * UNIFORM WORK: each block handles the q-tile PAIR {31-p, p} -> exactly
//    33 k-tile iterations for every block. 512 blocks x 256 thr = 2 blocks/CU,
//    8 waves/CU SUSTAINED (no drain tail; previously avg 3.6 waves/CU).
//  * 4 waves x 16 q-rows (was 2 x 32): per-wave serial chain per k-tile
//    halves (8 QK MFMA -> 16 exp2 -> 8 PV MFMA); K-frag LDS reads unchanged.
//  * Segment B's tile-0 staging is issued during segment A's last iteration
//    (into the free dbuf half) -> no DMA bubble at the segment switch; B's
//    k-range [0,p] is a subset of A's [0,31-p], so it re-reads L2-hot tiles.
//  * rs kept as 4 partials to break the serial fp32 add chain.
// No-max softmax (Q pre-scaled by log2e/8), direct O writes (no atomics).
// XCD-clustered mapping: g=bid&7 -> bh in [4g,4g+4) for L2-resident K/VT.
// ---------------------------------------------------------------------------
__global__ __launch_bounds__(256, 2) void attn_kernel(
    const bf16_t* __restrict__ Q, const bf16_t* __restrict__ K,
    const bf16_t* __restrict__ VT, bf16_t* __restrict__ O) {
  __shared__ __align__(16) bf16_t Ks[2][64 * 64];  // dbuf swizzled [key][d]
  __shared__ __align__(16) bf16_t Vt[2][64 * 64];  // dbuf swizzled [d][perm-key]

  const int tid = threadIdx.x;
  const int w = tid >> 6, l = tid & 63;
  const int lq = l & 15, qd = l >> 4;
  const int bid = blockIdx.x;
  const int g = bid & 7, t = bid >> 3;  // 64 blocks per XCD-group
  const int bh = g * 4 + (t & 3);       // 4 bh per XCD-group: L2-resident K/VT
  const int p = t >> 2;                 // pair index: q-tiles {31-p, p}
  const int b = bh >> 4, h = bh & 15;
  const size_t rowbase = (size_t)b * S;
  const bf16_t* Kg = K + rowbase * E + h * 64;
  const bf16_t* Vg = VT + (size_t)bh * 64 * S;

  // prefetch k-tile 0 into buffer 0
  stage_tile<64, 256>(Kg, E, Ks[0], tid);
  stage_tile<64, 256>(Vg, S, Vt[0], tid);
  int cb = 0;

#pragma unroll 1
  for (int seg = 0; seg < 2; ++seg) {
    const int qt = seg ? p : 31 - p;    // heavy q-tile first
    const int qr = qt * 64 + w * 16;    // wave rows [qr, qr+16)

    // Q fragments (pre-scaled), used as the MFMA B-operand: rows qr+lq
    bf16x8 aq[2];
#pragma unroll
    for (int ks = 0; ks < 2; ++ks)
      aq[ks] = *(const bf16x8*)(Q + (rowbase + qr + lq) * E + h * 64 +
                                ks * 32 + qd * 8);

    f32x4 oacc[4];
#pragma unroll
    for (int nt = 0; nt < 4; ++nt) oacc[nt] = (f32x4){0.f, 0.f, 0.f, 0.f};
    float rs4[4] = {0.f, 0.f, 0.f, 0.f};

    for (int kt = 0; kt <= qt; ++kt) {
      __syncthreads();  // own vmcnt(0) drains DMA into buffer cb; all waves'
                        // reads of buffer cb^1 (previous iter) are complete
      if (kt < qt) {    // stage tile kt+1 into the other buffer
        const int kn = (kt + 1) * 64;
        stage_tile<64, 256>(Kg + (size_t)kn * E, E, Ks[cb ^ 1], tid);
        stage_tile<64, 256>(Vg + kn, S, Vt[cb ^ 1], tid);
      } else if (seg == 0) {  // last A-iter: prefetch segment B's tile 0
        stage_tile<64, 256>(Kg, E, Ks[cb ^ 1], tid);
        stage_tile<64, 256>(Vg, S, Vt[cb ^ 1], tid);
      }
      const bf16_t* Kc = Ks[cb];
      const bf16_t* Vc = Vt[cb];
      const int k0 = kt * 64;
      const bool needmask = (kt == qt);  // exact: kt<qt => k0+63 < qr

      // ---- S^T = K * Q^T : 8 MFMA; lane holds q=lq, keys nt*16+qd*4+r ----
      f32x4 sacc[4];
#pragma unroll
      for (int nt = 0; nt < 4; ++nt) sacc[nt] = (f32x4){0.f, 0.f, 0.f, 0.f};
#pragma unroll
      for (int ks = 0; ks < 2; ++ks) {
        bf16x8 bk[4];
#pragma unroll
        for (int nt = 0; nt < 4; ++nt)
          bk[nt] = read_frag(Kc, nt * 16 + lq, ks * 4 + qd);
#pragma unroll
        for (int nt = 0; nt < 4; ++nt)
          sacc[nt] = MFMA16(bk[nt], aq[ks], sacc[nt]);
      }
      // ---- softmax in registers; pack directly into PV A-frags ----
      // ap[ks][j] = pv(nt = ks*2 + (j>>2), r = j&3)  [matches VT's sigma]
      bf16x8 ap[2];
#pragma unroll
      for (int nt = 0; nt < 4; ++nt)
#pragma unroll
        for (int r = 0; r < 4; ++r) {
          float pv = exp2f(sacc[nt][r]);
          if (needmask) {
            const int kg = k0 + nt * 16 + qd * 4 + r;  // key index
            const int qg = qr + lq;                    // query index
            pv = (kg > qg) ? 0.f : pv;
          }
          rs4[nt] += pv;
          ap[nt >> 1][((nt & 1) << 2) | r] = (bf16_t)pv;
        }
      // ---- O += P * V : 8 MFMA ----
#pragma unroll
      for (int ks = 0; ks < 2; ++ks) {
        bf16x8 bv[4];
#pragma unroll
        for (int nt = 0; nt < 4; ++nt)
          bv[nt] = read_frag(Vc, nt * 16 + lq, ks * 4 + qd);
#pragma unroll
        for (int nt = 0; nt < 4; ++nt)
          oacc[nt] = MFMA16(ap[ks], bv[nt], oacc[nt]);
      }
      cb ^= 1;
    }

    // row-sum totals: lane's rs is the partial for q-row lq over its qd's
    // keys; xor-16/32 sums the 4 qd groups. Then redistribute for the
    // C-layout write (lane needs rows qd*4+r, held by lanes lq = qd*4+r).
    float rs = (rs4[0] + rs4[1]) + (rs4[2] + rs4[3]);
    rs += __shfl_xor(rs, 16);
    rs += __shfl_xor(rs, 32);
    float rinv[4];
#pragma unroll
    for (int r = 0; r < 4; ++r) rinv[r] = 1.0f / __shfl(rs, qd * 4 + r);
#pragma unroll
    for (int nt = 0; nt < 4; ++nt)
#pragma unroll
      for (int r = 0; r < 4; ++r) {
        const int qg = qr + qd * 4 + r;
        O[(rowbase + qg) * E + h * 64 + nt * 16 + lq] =
            (bf16_t)(oacc[nt][r] * rinv[r]);
      }
  }
}

// ---------------------------------------------------------------------------
// launch
// ---------------------------------------------------------------------------
extern "C" void kernel_launch(void* const* d_in, const int* in_sizes, int n_in,
                              void* d_out, int out_size, void* d_ws, size_t ws_size,
                              hipStream_t stream) {
  const float* x  = (const float*)d_in[0];
  const float* Wq = (const float*)d_in[1];
  const float* bq = (const float*)d_in[2];
  const float* Wk = (const float*)d_in[3];
  const float* bk = (const float*)d_in[4];
  const float* Wv = (const float*)d_in[5];
  const float* bv = (const float*)d_in[6];
  const float* Wo = (const float*)d_in[7];
  const float* bo = (const float*)d_in[8];
  float* out = (float*)d_out;

  unsigned char* ws = (unsigned char*)d_ws;
  constexpr size_t MB = 1ull << 20;
  bf16_t* xb  = (bf16_t*)(ws + 0 * MB);   // 8 MB; reused as Ob after qkv
  bf16_t* wqb = (bf16_t*)(ws + 8 * MB);
  bf16_t* wkb = (bf16_t*)(ws + 10 * MB);
  bf16_t* wvb = (bf16_t*)(ws + 12 * MB);
  bf16_t* wob = (bf16_t*)(ws + 14 * MB);
  bf16_t* Qb  = (bf16_t*)(ws + 16 * MB);
  bf16_t* Kb  = (bf16_t*)(ws + 24 * MB);
  bf16_t* Vb  = (bf16_t*)(ws + 32 * MB);  // row-major V; dead after vtrans
  bf16_t* VT  = (bf16_t*)(ws + 40 * MB);  // [32 bh][64 d][2048 s, sigma-perm per 64]
  bf16_t* Ob  = xb;                       // xb dead after qkv

  cvt_all_kernel<<<4096 + 4 * 1024, 256, 0, stream>>>(
      x, Wq, Wk, Wv, Wo, xb, wqb, wkb, wvb, wob);

  qkv_gemm_kernel<<<dim3(24, 32), 256, 0, stream>>>(
      xb, wqb, wkb, wvb, bq, bk, bv, Qb, Kb, Vb);

  vtrans_kernel<<<dim3(32, 32), 256, 0, stream>>>(Vb, VT);

  attn_kernel<<<512, 256, 0, stream>>>(Qb, Kb, VT, Ob);

  oproj_gemm_kernel<<<dim3(8, 64), 256, 0, stream>>>(Ob, wob, bo, out);
}

// Round 2
// 183.437 us; speedup vs baseline: 1.1381x; 1.0391x over previous
//
#include <hip/hip_runtime.h>
#include <hip/hip_bf16.h>

typedef __bf16 bf16_t;
typedef __bf16 bf16x8 __attribute__((ext_vector_type(8)));
typedef __bf16 bf16x4 __attribute__((ext_vector_type(4)));
typedef float  f32x4  __attribute__((ext_vector_type(4)));

#define MFMA16(a, b, c) __builtin_amdgcn_mfma_f32_16x16x32_bf16((a), (b), (c), 0, 0, 0)

constexpr int E  = 1024;
constexpr int S  = 2048;
constexpr int H  = 16;
constexpr int M  = 4096;  // B*S

// ---------------------------------------------------------------------------
// async global->LDS 16B (wave-uniform LDS base + lane*16)
// ---------------------------------------------------------------------------
__device__ __forceinline__ void glds16(const bf16_t* src, bf16_t* dst) {
  __builtin_amdgcn_global_load_lds(
      (const __attribute__((address_space(1))) void*)src,
      (__attribute__((address_space(3))) void*)dst, 16, 0, 0);
}

// Stage a [ROWS x 64] bf16 tile (global row stride gld) into LDS, XOR-swizzled.
// NT = block threads.
template <int ROWS, int NT>
__device__ __forceinline__ void stage_tile(const bf16_t* g, int gld,
                                           bf16_t* lds, int tid) {
  const int w = tid >> 6, l = tid & 63;
#pragma unroll
  for (int i = 0; i < ROWS * 8 / NT; ++i) {
    const int c = i * NT + w * 64 + l;
    const int row = c >> 3;
    const int gch = (c & 7) ^ (row & 7);
    glds16(g + (size_t)row * gld + gch * 8, lds + (size_t)(i * NT + w * 64) * 8);
  }
}

// Read an 8-elem k-chunk (kc in [0,8)) of row `row` from a swizzled tile.
__device__ __forceinline__ bf16x8 read_frag(const bf16_t* lds, int row, int kc) {
  return *(const bf16x8*)(lds + (size_t)((row << 3) + (kc ^ (row & 7))) * 8);
}

// ---------------------------------------------------------------------------
// fused fp32->bf16 conversion for x + 4 weight matrices
// ---------------------------------------------------------------------------
__global__ void cvt_all_kernel(const float* __restrict__ x,
                               const float* __restrict__ w0, const float* __restrict__ w1,
                               const float* __restrict__ w2, const float* __restrict__ w3,
                               bf16_t* __restrict__ xb,
                               bf16_t* __restrict__ o0, bf16_t* __restrict__ o1,
                               bf16_t* __restrict__ o2, bf16_t* __restrict__ o3) {
  const int bid = blockIdx.x;
  const float* s;
  bf16_t* d;
  int idx;
  if (bid < 4096) {
    s = x; d = xb; idx = bid * 256 + threadIdx.x;
  } else {
    const int seg = (bid - 4096) >> 10;
    s = seg == 0 ? w0 : seg == 1 ? w1 : seg == 2 ? w2 : w3;
    d = seg == 0 ? o0 : seg == 1 ? o1 : seg == 2 ? o2 : o3;
    idx = ((bid - 4096) & 1023) * 256 + threadIdx.x;
  }
  float4 v = ((const float4*)s)[idx];
  bf16x4 o;
  o[0] = (bf16_t)v.x; o[1] = (bf16_t)v.y; o[2] = (bf16_t)v.z; o[3] = (bf16_t)v.w;
  ((bf16x4*)d)[idx] = o;
}

// ---------------------------------------------------------------------------
// fused QKV projection, v2: 256x192 tile, BK=64, 512 thr (8 waves = 2M x 4N),
// double-buffered LDS (112 KB), 4-phase-per-K-tile schedule with issue-early
// DMA staging (T3), per-phase barriers + setprio (T5), XOR swizzle (T2).
//
// W treated as fused [3072][1024] (wqb/wkb/wvb contiguous in workspace);
// outputs Qb/Kb/Vb contiguous [3][4096][1024]. Q PRE-SCALED by log2(e)/8.
//
// Grid: 256 blocks (16 m x 16 n) = exactly 1 block/CU. 4x4-region XCD
// swizzle keeps each XCD's A/B working set ~5 MB (mostly L2-resident).
//
// Schedule per K-tile g (slot s=g&1): 4 phases q=0..3 (mh=q>>1, kk=q&1):
//   { ds_read 4 A-frags + 3 B-frags of tile g;
//     issue DMA of tile g+1 into slot s^1 (q0: A rows 0-127, q1: A rows
//     128-255, q2: B all 192 rows);   <- issued 2-3 phases before needed
//     s_barrier; lgkmcnt(0); sched_barrier;
//     setprio(1); 12 MFMA (4mi x 3ni); setprio(0);
//     [q3 only: vmcnt(0) - residual wait, loads have had ~3 phases to land]
//     s_barrier; }
// Safety: DMA writes go to slot s^1 whose readers all passed the previous
// group's closing barrier; vmcnt(0)+barrier at q3 guarantees tile g+1 landed
// before any wave's next-group ds_read.
// ---------------------------------------------------------------------------
__global__ __launch_bounds__(512, 2) void qkv8_kernel(
    const bf16_t* __restrict__ xb, const bf16_t* __restrict__ W3,
    const float* __restrict__ bq, const float* __restrict__ bk,
    const float* __restrict__ bv, bf16_t* __restrict__ Qb) {
  __shared__ __align__(16) bf16_t As[2][256 * 64];  // 64 KB
  __shared__ __align__(16) bf16_t Bs[2][192 * 64];  // 48 KB
  const int tid = threadIdx.x;
  const int l = tid & 63, lq = l & 15, qd = l >> 4;
  const int w = tid >> 6, wm = w >> 2, wn = w & 3;

  // XCD-aware 4x4-region swizzle: xcd k owns regions {2k, 2k+1}
  const int wg = blockIdx.x;
  const int xcd = wg & 7, i5 = wg >> 3;        // i5 in [0,32)
  const int region = xcd * 2 + (i5 >> 4);      // [0,16), 4x4 block regions
  const int j = i5 & 15;
  const int bx = (region & 3) * 4 + (j & 3);   // n-tile [0,16)
  const int by = (region >> 2) * 4 + (j >> 2); // m-tile [0,16)
  const int m0 = by * 256, n0 = bx * 192;

  const bf16_t* Ag = xb + (size_t)m0 * E;
  const bf16_t* Bg = W3 + (size_t)n0 * E;

  f32x4 acc[8][3];
#pragma unroll
  for (int mi = 0; mi < 8; ++mi)
#pragma unroll
    for (int n = 0; n < 3; ++n) acc[mi][n] = (f32x4){0.f, 0.f, 0.f, 0.f};

  // prologue: stage K-tile 0 into slot 0
  stage_tile<256, 512>(Ag, E, As[0], tid);
  stage_tile<192, 512>(Bg, E, Bs[0], tid);
  asm volatile("s_waitcnt vmcnt(0)" ::: "memory");
  __builtin_amdgcn_s_barrier();

#pragma unroll 1
  for (int g = 0; g < 16; ++g) {
    const int s = g & 1;
    const bf16_t* Al = As[s];
    const bf16_t* Bl = Bs[s];
    bf16_t* An = As[s ^ 1];
    bf16_t* Bn = Bs[s ^ 1];
    const bf16_t* Agn = Ag + (g + 1) * 64;
    const bf16_t* Bgn = Bg + (g + 1) * 64;
    const bool more = (g < 15);
#pragma unroll
    for (int q = 0; q < 4; ++q) {
      const int mh = q >> 1, kk = q & 1;
      bf16x8 af[4], bfr[3];
#pragma unroll
      for (int jj = 0; jj < 4; ++jj)
        af[jj] = read_frag(Al, wm * 128 + (mh * 4 + jj) * 16 + lq, kk * 4 + qd);
#pragma unroll
      for (int n = 0; n < 3; ++n)
        bfr[n] = read_frag(Bl, wn * 48 + n * 16 + lq, kk * 4 + qd);
      if (more) {
        if (q == 0) stage_tile<128, 512>(Agn, E, An, tid);
        else if (q == 1) stage_tile<128, 512>(Agn + (size_t)128 * E, E, An + 128 * 64, tid);
        else if (q == 2) stage_tile<192, 512>(Bgn, E, Bn, tid);
      }
      __builtin_amdgcn_s_barrier();
      asm volatile("s_waitcnt lgkmcnt(0)" ::: "memory");
      __builtin_amdgcn_sched_barrier(0);
      __builtin_amdgcn_s_setprio(1);
#pragma unroll
      for (int jj = 0; jj < 4; ++jj)
#pragma unroll
        for (int n = 0; n < 3; ++n)
          acc[mh * 4 + jj][n] = MFMA16(af[jj], bfr[n], acc[mh * 4 + jj][n]);
      __builtin_amdgcn_s_setprio(0);
      if (q == 3 && more) asm volatile("s_waitcnt vmcnt(0)" ::: "memory");
      __builtin_amdgcn_s_barrier();
    }
  }

  // epilogue: bias (+ Q scale), write to contiguous Q/K/V
#pragma unroll
  for (int n = 0; n < 3; ++n) {
    const int col = n0 + wn * 48 + n * 16 + lq;
    const int mat = col >> 10, cc = col & 1023;
    const float bvv = (mat == 0 ? bq : mat == 1 ? bk : bv)[cc];
    const float sc = (mat == 0) ? 0.18033688011112043f : 1.0f;  // log2(e)/8
    bf16_t* Out = Qb + (size_t)mat * ((size_t)M * E);
#pragma unroll
    for (int mi = 0; mi < 8; ++mi)
#pragma unroll
      for (int r = 0; r < 4; ++r) {
        const int row = m0 + wm * 128 + mi * 16 + qd * 4 + r;
        Out[(size_t)row * E + cc] = (bf16_t)((acc[mi][n][r] + bvv) * sc);
      }
  }
}

// ---------------------------------------------------------------------------
// V transpose: Vb [4096,1024] -> VT[bh][d][s], keys sigma-permuted per 64:
// VT[bh][d][64*blk + p] = V[64*blk + sigma(p)][d],
// sigma(p) = ((p>>5)*2 + ((p&7)>>2))*16 + ((p>>3)&3)*4 + (p&3)
// (chosen so that the attn kernel's S^T accumulator registers are directly
// the PV A-fragment; inverse: sl = a*16+b*4+c -> p = (a>>1)*32+b*8+(a&1)*4+c).
// ---------------------------------------------------------------------------
__global__ __launch_bounds__(256) void vtrans_kernel(const bf16_t* __restrict__ Vb,
                                                     bf16_t* __restrict__ VT) {
  constexpr int LDT = 72;
  __shared__ __align__(16) bf16_t T[64 * LDT];  // T[p][d] = V[s0+sigma(p)][d]
  const int tid = threadIdx.x;
  const int st = blockIdx.x, bh = blockIdx.y;
  const int b = bh >> 4, h = bh & 15;
  const int s0 = st * 64;
  const size_t rowbase = (size_t)b * S;
#pragma unroll
  for (int i = 0; i < 2; ++i) {
    const int c = i * 256 + tid;
    const int sl = c >> 3, dp = c & 7;
    const int a = sl >> 4, bb = (sl >> 2) & 3, cc = sl & 3;
    const int p = (a >> 1) * 32 + bb * 8 + (a & 1) * 4 + cc;  // sigma^-1(sl)
    bf16x8 v = *(const bf16x8*)(Vb + (rowbase + s0 + sl) * E + h * 64 + dp * 8);
    *(bf16x8*)&T[p * LDT + dp * 8] = v;
  }
  __syncthreads();
#pragma unroll
  for (int i = 0; i < 2; ++i) {
    const int c = i * 256 + tid;
    const int d = c >> 3, pp = (c & 7) * 8;
    bf16x8 o;
#pragma unroll
    for (int j = 0; j < 8; ++j) o[j] = T[(pp + j) * LDT + d];
    *(bf16x8*)&VT[((size_t)bh * 64 + d) * S + s0 + pp] = o;
  }
}

// ---------------------------------------------------------------------------
// output projection: 64x128 tiles -> grid (8, 64) = 512 blocks.
// ---------------------------------------------------------------------------
__global__ __launch_bounds__(256) void oproj_gemm_kernel(
    const bf16_t* __restrict__ Ob, const bf16_t* __restrict__ wo,
    const float* __restrict__ bo, float* __restrict__ out) {
  __shared__ __align__(16) bf16_t As[64 * 64];    // 8 KB
  __shared__ __align__(16) bf16_t Bs[128 * 64];   // 16 KB
  const int tid = threadIdx.x;
  const int n0 = blockIdx.x * 128;
  const int m0 = blockIdx.y * 64;
  const int w = tid >> 6, l = tid & 63, lq = l & 15, qd = l >> 4;
  const int wr = (w >> 1) * 32, wc = (w & 1) * 64;

  f32x4 acc[2][4];
#pragma unroll
  for (int i = 0; i < 2; ++i)
#pragma unroll
    for (int j = 0; j < 4; ++j) acc[i][j] = (f32x4){0.f, 0.f, 0.f, 0.f};

  for (int kt = 0; kt < 16; ++kt) {
    __syncthreads();
    stage_tile<64, 256>(Ob + (size_t)m0 * E + kt * 64, E, As, tid);
    stage_tile<128, 256>(wo + (size_t)n0 * E + kt * 64, E, Bs, tid);
    __syncthreads();
#pragma unroll
    for (int ks = 0; ks < 2; ++ks) {
      bf16x8 af[2], bw[4];
#pragma unroll
      for (int mi = 0; mi < 2; ++mi)
        af[mi] = read_frag(As, wr + mi * 16 + lq, ks * 4 + qd);
#pragma unroll
      for (int ni = 0; ni < 4; ++ni)
        bw[ni] = read_frag(Bs, wc + ni * 16 + lq, ks * 4 + qd);
#pragma unroll
      for (int mi = 0; mi < 2; ++mi)
#pragma unroll
        for (int ni = 0; ni < 4; ++ni)
          acc[mi][ni] = MFMA16(af[mi], bw[ni], acc[mi][ni]);
    }
  }
#pragma unroll
  for (int ni = 0; ni < 4; ++ni) {
    const int col = n0 + wc + ni * 16 + lq;
    const float bvv = bo[col];
#pragma unroll
    for (int mi = 0; mi < 2; ++mi)
#pragma unroll
      for (int r = 0; r < 4; ++r) {
        const int row = m0 + wr + mi * 16 + qd * 4 + r;
        out[(size_t)row * E + col] = acc[mi][ni][r] + bvv;
      }
  }
}

// ---------------------------------------------------------------------------
// causal flash attention v12: operand-swapped S^T = K*Q^T (softmax'd regs ARE
// the PV A-fragment; keys sigma-permuted in VT; P never touches LDS).
// Uniform work: each block handles the q-tile PAIR {31-p, p} -> exactly 33
// k-tile iterations for every block. 512 blocks x 256 thr = 2 blocks/CU,
// 8 waves/CU sustained. 4 waves x 16 q-rows. Segment B's tile-0 staging is
// issued during segment A's last iteration (no DMA bubble at the switch).
// No-max softmax (Q pre-scaled by log2e/8), direct O writes (no atomics).
// XCD-clustered mapping: g=bid&7 -> bh in [4g,4g+4) for L2-resident K/VT.
// ---------------------------------------------------------------------------
__global__ __launch_bounds__(256, 2) void attn_kernel(
    const bf16_t* __restrict__ Q, const bf16_t* __restrict__ K,
    const bf16_t* __restrict__ VT, bf16_t* __restrict__ O) {
  __shared__ __align__(16) bf16_t Ks[2][64 * 64];  // dbuf swizzled [key][d]
  __shared__ __align__(16) bf16_t Vt[2][64 * 64];  // dbuf swizzled [d][perm-key]

  const int tid = threadIdx.x;
  const int w = tid >> 6, l = tid & 63;
  const int lq = l & 15, qd = l >> 4;
  const int bid = blockIdx.x;
  const int g = bid & 7, t = bid >> 3;  // 64 blocks per XCD-group
  const int bh = g * 4 + (t & 3);       // 4 bh per XCD-group: L2-resident K/VT
  const int p = t >> 2;                 // pair index: q-tiles {31-p, p}
  const int b = bh >> 4, h = bh & 15;
  const size_t rowbase = (size_t)b * S;
  const bf16_t* Kg = K + rowbase * E + h * 64;
  const bf16_t* Vg = VT + (size_t)bh * 64 * S;

  // prefetch k-tile 0 into buffer 0
  stage_tile<64, 256>(Kg, E, Ks[0], tid);
  stage_tile<64, 256>(Vg, S, Vt[0], tid);
  int cb = 0;

#pragma unroll 1
  for (int seg = 0; seg < 2; ++seg) {
    const int qt = seg ? p : 31 - p;    // heavy q-tile first
    const int qr = qt * 64 + w * 16;    // wave rows [qr, qr+16)

    // Q fragments (pre-scaled), used as the MFMA B-operand: rows qr+lq
    bf16x8 aq[2];
#pragma unroll
    for (int ks = 0; ks < 2; ++ks)
      aq[ks] = *(const bf16x8*)(Q + (rowbase + qr + lq) * E + h * 64 +
                                ks * 32 + qd * 8);

    f32x4 oacc[4];
#pragma unroll
    for (int nt = 0; nt < 4; ++nt) oacc[nt] = (f32x4){0.f, 0.f, 0.f, 0.f};
    float rs4[4] = {0.f, 0.f, 0.f, 0.f};

    for (int kt = 0; kt <= qt; ++kt) {
      __syncthreads();  // own vmcnt(0) drains DMA into buffer cb; all waves'
                        // reads of buffer cb^1 (previous iter) are complete
      if (kt < qt) {    // stage tile kt+1 into the other buffer
        const int kn = (kt + 1) * 64;
        stage_tile<64, 256>(Kg + (size_t)kn * E, E, Ks[cb ^ 1], tid);
        stage_tile<64, 256>(Vg + kn, S, Vt[cb ^ 1], tid);
      } else if (seg == 0) {  // last A-iter: prefetch segment B's tile 0
        stage_tile<64, 256>(Kg, E, Ks[cb ^ 1], tid);
        stage_tile<64, 256>(Vg, S, Vt[cb ^ 1], tid);
      }
      const bf16_t* Kc = Ks[cb];
      const bf16_t* Vc = Vt[cb];
      const int k0 = kt * 64;
      const bool needmask = (kt == qt);  // exact: kt<qt => k0+63 < qr

      // ---- S^T = K * Q^T : 8 MFMA; lane holds q=lq, keys nt*16+qd*4+r ----
      f32x4 sacc[4];
#pragma unroll
      for (int nt = 0; nt < 4; ++nt) sacc[nt] = (f32x4){0.f, 0.f, 0.f, 0.f};
#pragma unroll
      for (int ks = 0; ks < 2; ++ks) {
        bf16x8 bk[4];
#pragma unroll
        for (int nt = 0; nt < 4; ++nt)
          bk[nt] = read_frag(Kc, nt * 16 + lq, ks * 4 + qd);
#pragma unroll
        for (int nt = 0; nt < 4; ++nt)
          sacc[nt] = MFMA16(bk[nt], aq[ks], sacc[nt]);
      }
      // ---- softmax in registers; pack directly into PV A-frags ----
      // ap[ks][j] = pv(nt = ks*2 + (j>>2), r = j&3)  [matches VT's sigma]
      bf16x8 ap[2];
#pragma unroll
      for (int nt = 0; nt < 4; ++nt)
#pragma unroll
        for (int r = 0; r < 4; ++r) {
          float pv = exp2f(sacc[nt][r]);
          if (needmask) {
            const int kg = k0 + nt * 16 + qd * 4 + r;  // key index
            const int qg = qr + lq;                    // query index
            pv = (kg > qg) ? 0.f : pv;
          }
          rs4[nt] += pv;
          ap[nt >> 1][((nt & 1) << 2) | r] = (bf16_t)pv;
        }
      // ---- O += P * V : 8 MFMA ----
#pragma unroll
      for (int ks = 0; ks < 2; ++ks) {
        bf16x8 bv[4];
#pragma unroll
        for (int nt = 0; nt < 4; ++nt)
          bv[nt] = read_frag(Vc, nt * 16 + lq, ks * 4 + qd);
#pragma unroll
        for (int nt = 0; nt < 4; ++nt)
          oacc[nt] = MFMA16(ap[ks], bv[nt], oacc[nt]);
      }
      cb ^= 1;
    }

    // row-sum totals: lane's rs is the partial for q-row lq over its qd's
    // keys; xor-16/32 sums the 4 qd groups. Then redistribute for the
    // C-layout write (lane needs rows qd*4+r, held by lanes lq = qd*4+r).
    float rs = (rs4[0] + rs4[1]) + (rs4[2] + rs4[3]);
    rs += __shfl_xor(rs, 16);
    rs += __shfl_xor(rs, 32);
    float rinv[4];
#pragma unroll
    for (int r = 0; r < 4; ++r) rinv[r] = 1.0f / __shfl(rs, qd * 4 + r);
#pragma unroll
    for (int nt = 0; nt < 4; ++nt)
#pragma unroll
      for (int r = 0; r < 4; ++r) {
        const int qg = qr + qd * 4 + r;
        O[(rowbase + qg) * E + h * 64 + nt * 16 + lq] =
            (bf16_t)(oacc[nt][r] * rinv[r]);
      }
  }
}

// ---------------------------------------------------------------------------
// launch
// ---------------------------------------------------------------------------
extern "C" void kernel_launch(void* const* d_in, const int* in_sizes, int n_in,
                              void* d_out, int out_size, void* d_ws, size_t ws_size,
                              hipStream_t stream) {
  const float* x  = (const float*)d_in[0];
  const float* Wq = (const float*)d_in[1];
  const float* bq = (const float*)d_in[2];
  const float* Wk = (const float*)d_in[3];
  const float* bk = (const float*)d_in[4];
  const float* Wv = (const float*)d_in[5];
  const float* bv = (const float*)d_in[6];
  const float* Wo = (const float*)d_in[7];
  const float* bo = (const float*)d_in[8];
  float* out = (float*)d_out;

  unsigned char* ws = (unsigned char*)d_ws;
  constexpr size_t MB = 1ull << 20;
  bf16_t* xb  = (bf16_t*)(ws + 0 * MB);   // 8 MB; reused as Ob after qkv
  bf16_t* wqb = (bf16_t*)(ws + 8 * MB);   // wq/wk/wv contiguous [3072][1024]
  bf16_t* wkb = (bf16_t*)(ws + 10 * MB);
  bf16_t* wvb = (bf16_t*)(ws + 12 * MB);
  bf16_t* wob = (bf16_t*)(ws + 14 * MB);
  bf16_t* Qb  = (bf16_t*)(ws + 16 * MB);  // Q/K/V contiguous [3][4096][1024]
  bf16_t* Kb  = (bf16_t*)(ws + 24 * MB);
  bf16_t* Vb  = (bf16_t*)(ws + 32 * MB);  // row-major V; dead after vtrans
  bf16_t* VT  = (bf16_t*)(ws + 40 * MB);  // [32 bh][64 d][2048 s, sigma-perm per 64]
  bf16_t* Ob  = xb;                       // xb dead after qkv

  cvt_all_kernel<<<4096 + 4 * 1024, 256, 0, stream>>>(
      x, Wq, Wk, Wv, Wo, xb, wqb, wkb, wvb, wob);

  qkv8_kernel<<<256, 512, 0, stream>>>(xb, wqb, bq, bk, bv, Qb);

  vtrans_kernel<<<dim3(32, 32), 256, 0, stream>>>(Vb, VT);

  attn_kernel<<<512, 256, 0, stream>>>(Qb, Kb, VT, Ob);

  oproj_gemm_kernel<<<dim3(8, 64), 256, 0, stream>>>(Ob, wob, bo, out);
}

// Round 3
// 180.637 us; speedup vs baseline: 1.1557x; 1.0155x over previous
//
#include <hip/hip_runtime.h>
#include <hip/hip_bf16.h>

typedef __bf16 bf16_t;
typedef __bf16 bf16x8 __attribute__((ext_vector_type(8)));
typedef __bf16 bf16x4 __attribute__((ext_vector_type(4)));
typedef float  f32x4  __attribute__((ext_vector_type(4)));

#define MFMA16(a, b, c) __builtin_amdgcn_mfma_f32_16x16x32_bf16((a), (b), (c), 0, 0, 0)

constexpr int E  = 1024;
constexpr int S  = 2048;
constexpr int H  = 16;
constexpr int M  = 4096;  // B*S

// ---------------------------------------------------------------------------
// async global->LDS 16B (wave-uniform LDS base + lane*16)
// ---------------------------------------------------------------------------
__device__ __forceinline__ void glds16(const bf16_t* src, bf16_t* dst) {
  __builtin_amdgcn_global_load_lds(
      (const __attribute__((address_space(1))) void*)src,
      (__attribute__((address_space(3))) void*)dst, 16, 0, 0);
}

// Stage a [ROWS x 64] bf16 tile (global row stride gld) into LDS, XOR-swizzled.
// NT = block threads.
template <int ROWS, int NT>
__device__ __forceinline__ void stage_tile(const bf16_t* g, int gld,
                                           bf16_t* lds, int tid) {
  const int w = tid >> 6, l = tid & 63;
#pragma unroll
  for (int i = 0; i < ROWS * 8 / NT; ++i) {
    const int c = i * NT + w * 64 + l;
    const int row = c >> 3;
    const int gch = (c & 7) ^ (row & 7);
    glds16(g + (size_t)row * gld + gch * 8, lds + (size_t)(i * NT + w * 64) * 8);
  }
}

// Read an 8-elem k-chunk (kc in [0,8)) of row `row` from a swizzled tile.
__device__ __forceinline__ bf16x8 read_frag(const bf16_t* lds, int row, int kc) {
  return *(const bf16x8*)(lds + (size_t)((row << 3) + (kc ^ (row & 7))) * 8);
}

// ---------------------------------------------------------------------------
// fused fp32->bf16 conversion for x + 4 weight matrices
// ---------------------------------------------------------------------------
__global__ void cvt_all_kernel(const float* __restrict__ x,
                               const float* __restrict__ w0, const float* __restrict__ w1,
                               const float* __restrict__ w2, const float* __restrict__ w3,
                               bf16_t* __restrict__ xb,
                               bf16_t* __restrict__ o0, bf16_t* __restrict__ o1,
                               bf16_t* __restrict__ o2, bf16_t* __restrict__ o3) {
  const int bid = blockIdx.x;
  const float* s;
  bf16_t* d;
  int idx;
  if (bid < 4096) {
    s = x; d = xb; idx = bid * 256 + threadIdx.x;
  } else {
    const int seg = (bid - 4096) >> 10;
    s = seg == 0 ? w0 : seg == 1 ? w1 : seg == 2 ? w2 : w3;
    d = seg == 0 ? o0 : seg == 1 ? o1 : seg == 2 ? o2 : o3;
    idx = ((bid - 4096) & 1023) * 256 + threadIdx.x;
  }
  float4 v = ((const float4*)s)[idx];
  bf16x4 o;
  o[0] = (bf16_t)v.x; o[1] = (bf16_t)v.y; o[2] = (bf16_t)v.z; o[3] = (bf16_t)v.w;
  ((bf16x4*)d)[idx] = o;
}

// ---------------------------------------------------------------------------
// fused QKV projection, v2: 256x192 tile, BK=64, 512 thr (8 waves = 2M x 4N),
// double-buffered LDS (112 KB), 4-phase-per-K-tile schedule with issue-early
// DMA staging (T3), per-phase barriers + setprio (T5), XOR swizzle (T2).
// W fused [3072][1024]; outputs Q/K/V contiguous [3][4096][1024].
// Q PRE-SCALED by log2(e)/8. Grid 256 = 1 block/CU, 4x4-region XCD swizzle.
// ---------------------------------------------------------------------------
__global__ __launch_bounds__(512, 2) void qkv8_kernel(
    const bf16_t* __restrict__ xb, const bf16_t* __restrict__ W3,
    const float* __restrict__ bq, const float* __restrict__ bk,
    const float* __restrict__ bv, bf16_t* __restrict__ Qb) {
  __shared__ __align__(16) bf16_t As[2][256 * 64];  // 64 KB
  __shared__ __align__(16) bf16_t Bs[2][192 * 64];  // 48 KB
  const int tid = threadIdx.x;
  const int l = tid & 63, lq = l & 15, qd = l >> 4;
  const int w = tid >> 6, wm = w >> 2, wn = w & 3;

  // XCD-aware 4x4-region swizzle: xcd k owns regions {2k, 2k+1}
  const int wg = blockIdx.x;
  const int xcd = wg & 7, i5 = wg >> 3;        // i5 in [0,32)
  const int region = xcd * 2 + (i5 >> 4);      // [0,16), 4x4 block regions
  const int j = i5 & 15;
  const int bx = (region & 3) * 4 + (j & 3);   // n-tile [0,16)
  const int by = (region >> 2) * 4 + (j >> 2); // m-tile [0,16)
  const int m0 = by * 256, n0 = bx * 192;

  const bf16_t* Ag = xb + (size_t)m0 * E;
  const bf16_t* Bg = W3 + (size_t)n0 * E;

  f32x4 acc[8][3];
#pragma unroll
  for (int mi = 0; mi < 8; ++mi)
#pragma unroll
    for (int n = 0; n < 3; ++n) acc[mi][n] = (f32x4){0.f, 0.f, 0.f, 0.f};

  // prologue: stage K-tile 0 into slot 0
  stage_tile<256, 512>(Ag, E, As[0], tid);
  stage_tile<192, 512>(Bg, E, Bs[0], tid);
  asm volatile("s_waitcnt vmcnt(0)" ::: "memory");
  __builtin_amdgcn_s_barrier();

#pragma unroll 1
  for (int g = 0; g < 16; ++g) {
    const int s = g & 1;
    const bf16_t* Al = As[s];
    const bf16_t* Bl = Bs[s];
    bf16_t* An = As[s ^ 1];
    bf16_t* Bn = Bs[s ^ 1];
    const bf16_t* Agn = Ag + (g + 1) * 64;
    const bf16_t* Bgn = Bg + (g + 1) * 64;
    const bool more = (g < 15);
#pragma unroll
    for (int q = 0; q < 4; ++q) {
      const int mh = q >> 1, kk = q & 1;
      bf16x8 af[4], bfr[3];
#pragma unroll
      for (int jj = 0; jj < 4; ++jj)
        af[jj] = read_frag(Al, wm * 128 + (mh * 4 + jj) * 16 + lq, kk * 4 + qd);
#pragma unroll
      for (int n = 0; n < 3; ++n)
        bfr[n] = read_frag(Bl, wn * 48 + n * 16 + lq, kk * 4 + qd);
      if (more) {
        if (q == 0) stage_tile<128, 512>(Agn, E, An, tid);
        else if (q == 1) stage_tile<128, 512>(Agn + (size_t)128 * E, E, An + 128 * 64, tid);
        else if (q == 2) stage_tile<192, 512>(Bgn, E, Bn, tid);
      }
      __builtin_amdgcn_s_barrier();
      asm volatile("s_waitcnt lgkmcnt(0)" ::: "memory");
      __builtin_amdgcn_sched_barrier(0);
      __builtin_amdgcn_s_setprio(1);
#pragma unroll
      for (int jj = 0; jj < 4; ++jj)
#pragma unroll
        for (int n = 0; n < 3; ++n)
          acc[mh * 4 + jj][n] = MFMA16(af[jj], bfr[n], acc[mh * 4 + jj][n]);
      __builtin_amdgcn_s_setprio(0);
      if (q == 3 && more) asm volatile("s_waitcnt vmcnt(0)" ::: "memory");
      __builtin_amdgcn_s_barrier();
    }
  }

  // epilogue: bias (+ Q scale), write to contiguous Q/K/V
#pragma unroll
  for (int n = 0; n < 3; ++n) {
    const int col = n0 + wn * 48 + n * 16 + lq;
    const int mat = col >> 10, cc = col & 1023;
    const float bvv = (mat == 0 ? bq : mat == 1 ? bk : bv)[cc];
    const float sc = (mat == 0) ? 0.18033688011112043f : 1.0f;  // log2(e)/8
    bf16_t* Out = Qb + (size_t)mat * ((size_t)M * E);
#pragma unroll
    for (int mi = 0; mi < 8; ++mi)
#pragma unroll
      for (int r = 0; r < 4; ++r) {
        const int row = m0 + wm * 128 + mi * 16 + qd * 4 + r;
        Out[(size_t)row * E + cc] = (bf16_t)((acc[mi][n][r] + bvv) * sc);
      }
  }
}

// ---------------------------------------------------------------------------
// V transpose: Vb [4096,1024] -> VT[bh][d][s], keys sigma-permuted per 64:
// VT[bh][d][64*blk + p] = V[64*blk + sigma(p)][d],
// sigma(p) = ((p>>5)*2 + ((p&7)>>2))*16 + ((p>>3)&3)*4 + (p&3)
// ---------------------------------------------------------------------------
__global__ __launch_bounds__(256) void vtrans_kernel(const bf16_t* __restrict__ Vb,
                                                     bf16_t* __restrict__ VT) {
  constexpr int LDT = 72;
  __shared__ __align__(16) bf16_t T[64 * LDT];  // T[p][d] = V[s0+sigma(p)][d]
  const int tid = threadIdx.x;
  const int st = blockIdx.x, bh = blockIdx.y;
  const int b = bh >> 4, h = bh & 15;
  const int s0 = st * 64;
  const size_t rowbase = (size_t)b * S;
#pragma unroll
  for (int i = 0; i < 2; ++i) {
    const int c = i * 256 + tid;
    const int sl = c >> 3, dp = c & 7;
    const int a = sl >> 4, bb = (sl >> 2) & 3, cc = sl & 3;
    const int p = (a >> 1) * 32 + bb * 8 + (a & 1) * 4 + cc;  // sigma^-1(sl)
    bf16x8 v = *(const bf16x8*)(Vb + (rowbase + s0 + sl) * E + h * 64 + dp * 8);
    *(bf16x8*)&T[p * LDT + dp * 8] = v;
  }
  __syncthreads();
#pragma unroll
  for (int i = 0; i < 2; ++i) {
    const int c = i * 256 + tid;
    const int d = c >> 3, pp = (c & 7) * 8;
    bf16x8 o;
#pragma unroll
    for (int j = 0; j < 8; ++j) o[j] = T[(pp + j) * LDT + d];
    *(bf16x8*)&VT[((size_t)bh * 64 + d) * S + s0 + pp] = o;
  }
}

// ---------------------------------------------------------------------------
// output projection: 64x128 tiles -> grid (8, 64) = 512 blocks.
// ---------------------------------------------------------------------------
__global__ __launch_bounds__(256) void oproj_gemm_kernel(
    const bf16_t* __restrict__ Ob, const bf16_t* __restrict__ wo,
    const float* __restrict__ bo, float* __restrict__ out) {
  __shared__ __align__(16) bf16_t As[64 * 64];    // 8 KB
  __shared__ __align__(16) bf16_t Bs[128 * 64];   // 16 KB
  const int tid = threadIdx.x;
  const int n0 = blockIdx.x * 128;
  const int m0 = blockIdx.y * 64;
  const int w = tid >> 6, l = tid & 63, lq = l & 15, qd = l >> 4;
  const int wr = (w >> 1) * 32, wc = (w & 1) * 64;

  f32x4 acc[2][4];
#pragma unroll
  for (int i = 0; i < 2; ++i)
#pragma unroll
    for (int j = 0; j < 4; ++j) acc[i][j] = (f32x4){0.f, 0.f, 0.f, 0.f};

  for (int kt = 0; kt < 16; ++kt) {
    __syncthreads();
    stage_tile<64, 256>(Ob + (size_t)m0 * E + kt * 64, E, As, tid);
    stage_tile<128, 256>(wo + (size_t)n0 * E + kt * 64, E, Bs, tid);
    __syncthreads();
#pragma unroll
    for (int ks = 0; ks < 2; ++ks) {
      bf16x8 af[2], bw[4];
#pragma unroll
      for (int mi = 0; mi < 2; ++mi)
        af[mi] = read_frag(As, wr + mi * 16 + lq, ks * 4 + qd);
#pragma unroll
      for (int ni = 0; ni < 4; ++ni)
        bw[ni] = read_frag(Bs, wc + ni * 16 + lq, ks * 4 + qd);
#pragma unroll
      for (int mi = 0; mi < 2; ++mi)
#pragma unroll
        for (int ni = 0; ni < 4; ++ni)
          acc[mi][ni] = MFMA16(af[mi], bw[ni], acc[mi][ni]);
    }
  }
#pragma unroll
  for (int ni = 0; ni < 4; ++ni) {
    const int col = n0 + wc + ni * 16 + lq;
    const float bvv = bo[col];
#pragma unroll
    for (int mi = 0; mi < 2; ++mi)
#pragma unroll
      for (int r = 0; r < 4; ++r) {
        const int row = m0 + wr + mi * 16 + qd * 4 + r;
        out[(size_t)row * E + col] = acc[mi][ni][r] + bvv;
      }
  }
}

// ---------------------------------------------------------------------------
// causal flash attention v13: operand-swapped S^T = K*Q^T (softmax'd regs ARE
// the PV A-fragment; keys sigma-permuted in VT; P never touches LDS).
//
// v13 changes vs v12 (43.6 us, MfmaUtil 15%, VALUBusy 46% = serial chain):
//  * T15 PIPELINE: PV of tile kt-1 executes during iteration kt, overlapping
//    the softmax VALU of tile kt (independent dataflow). V is TRIPLE-buffered
//    (slots kt-1 / kt / kt+1 all live; 40 KB LDS, still 2 blocks/CU).
//  * ROW-SUM VIA MFMA: rs = P x ones via 1 extra MFMA per ks (constant ones
//    B-frag, no LDS). Output layout row=qd*4+r is exactly the O-write layout
//    -> kills 16 VALU adds/tile AND the end-of-segment shuffle redistribute.
//    rs now sums the same bf16-rounded P as the numerator (error cancels).
//  * __builtin_amdgcn_exp2f: single v_exp_f32 per element.
//  * setprio(1) around the QK+PV MFMA cluster (pipeline creates the wave
//    role-split that makes T5 pay).
// Uniform work: block = q-tile pair {31-p, p} = 33 k-tiles. 512 blocks x
// 256 thr = 2 blocks/CU, 8 waves/CU sustained. No-max softmax (Q pre-scaled
// by log2e/8). XCD-clustered mapping: g=bid&7 -> bh in [4g,4g+4).
// ---------------------------------------------------------------------------
__global__ __launch_bounds__(256, 2) void attn_kernel(
    const bf16_t* __restrict__ Q, const bf16_t* __restrict__ K,
    const bf16_t* __restrict__ VT, bf16_t* __restrict__ O) {
  __shared__ __align__(16) bf16_t Ks[2][64 * 64];  // K dbuf, swizzled [key][d]
  __shared__ __align__(16) bf16_t Vt[3][64 * 64];  // V tri-buf, swizzled [d][perm-key]

  const int tid = threadIdx.x;
  const int w = tid >> 6, l = tid & 63;
  const int lq = l & 15, qd = l >> 4;
  const int bid = blockIdx.x;
  const int g = bid & 7, t = bid >> 3;  // 64 blocks per XCD-group
  const int bh = g * 4 + (t & 3);       // 4 bh per XCD-group: L2-resident K/VT
  const int p = t >> 2;                 // pair index: q-tiles {31-p, p}
  const int b = bh >> 4, h = bh & 15;
  const size_t rowbase = (size_t)b * S;
  const bf16_t* Kg = K + rowbase * E + h * 64;
  const bf16_t* Vg = VT + (size_t)bh * 64 * S;

  // constant all-ones B-fragment for the row-sum MFMA
  bf16x8 ones;
#pragma unroll
  for (int j = 0; j < 8; ++j) ones[j] = (bf16_t)1.0f;

  // prefetch k-tile 0 into K slot 0 / V slot 0
  stage_tile<64, 256>(Kg, E, Ks[0], tid);
  stage_tile<64, 256>(Vg, S, Vt[0], tid);
  int cb = 0;    // K slot of current tile
  int vcur = 0;  // V slot of current tile

#pragma unroll 1
  for (int seg = 0; seg < 2; ++seg) {
    const int qt = seg ? p : 31 - p;    // heavy q-tile first
    const int qr = qt * 64 + w * 16;    // wave rows [qr, qr+16)

    // Q fragments (pre-scaled), used as the MFMA B-operand: rows qr+lq
    bf16x8 aq[2];
#pragma unroll
    for (int ks = 0; ks < 2; ++ks)
      aq[ks] = *(const bf16x8*)(Q + (rowbase + qr + lq) * E + h * 64 +
                                ks * 32 + qd * 8);

    f32x4 oacc[4];
#pragma unroll
    for (int nt = 0; nt < 4; ++nt) oacc[nt] = (f32x4){0.f, 0.f, 0.f, 0.f};
    f32x4 osum = (f32x4){0.f, 0.f, 0.f, 0.f};  // row sums via ones-MFMA
    bf16x8 ap_prev[2];                          // P frags of tile kt-1
    int vprev = vcur;

    // PV of the previous tile from V slot vp (reads ap_prev; accumulates
    // oacc + osum). Issued right after QK so its MFMAs overlap softmax VALU.
    auto do_pv = [&](const bf16_t* Vp) {
#pragma unroll
      for (int ks = 0; ks < 2; ++ks) {
        bf16x8 bv[4];
#pragma unroll
        for (int nt = 0; nt < 4; ++nt)
          bv[nt] = read_frag(Vp, nt * 16 + lq, ks * 4 + qd);
#pragma unroll
        for (int nt = 0; nt < 4; ++nt)
          oacc[nt] = MFMA16(ap_prev[ks], bv[nt], oacc[nt]);
        osum = MFMA16(ap_prev[ks], ones, osum);
      }
    };

    for (int kt = 0; kt <= qt; ++kt) {
      __syncthreads();  // own vmcnt(0) drains DMA into K[cb]/V[vcur]; all
                        // waves' reads of the slots being rewritten are done
      const int vnext = (vcur + 1 == 3) ? 0 : vcur + 1;
      if (kt < qt) {    // stage tile kt+1
        const int kn = (kt + 1) * 64;
        stage_tile<64, 256>(Kg + (size_t)kn * E, E, Ks[cb ^ 1], tid);
        stage_tile<64, 256>(Vg + kn, S, Vt[vnext], tid);
      } else if (seg == 0) {  // last A-iter: prefetch segment B's tile 0
        stage_tile<64, 256>(Kg, E, Ks[cb ^ 1], tid);
        stage_tile<64, 256>(Vg, S, Vt[vnext], tid);
      }
      const bf16_t* Kc = Ks[cb];
      const int k0 = kt * 64;
      const bool needmask = (kt == qt);  // exact: kt<qt => k0+63 < qr

      // ---- S^T = K * Q^T : 8 MFMA; lane holds q=lq, keys nt*16+qd*4+r ----
      f32x4 sacc[4];
#pragma unroll
      for (int nt = 0; nt < 4; ++nt) sacc[nt] = (f32x4){0.f, 0.f, 0.f, 0.f};
      __builtin_amdgcn_s_setprio(1);
#pragma unroll
      for (int ks = 0; ks < 2; ++ks) {
        bf16x8 bk[4];
#pragma unroll
        for (int nt = 0; nt < 4; ++nt)
          bk[nt] = read_frag(Kc, nt * 16 + lq, ks * 4 + qd);
#pragma unroll
        for (int nt = 0; nt < 4; ++nt)
          sacc[nt] = MFMA16(bk[nt], aq[ks], sacc[nt]);
      }
      // ---- PV of tile kt-1 (independent of softmax below; overlaps it) ----
      if (kt > 0) do_pv(Vt[vprev]);
      __builtin_amdgcn_s_setprio(0);

      // ---- softmax in registers; pack directly into next PV A-frags ----
      // ap[ks][j] = pv(nt = ks*2 + (j>>2), r = j&3)  [matches VT's sigma]
#pragma unroll
      for (int nt = 0; nt < 4; ++nt)
#pragma unroll
        for (int r = 0; r < 4; ++r) {
          float pv = __builtin_amdgcn_exp2f(sacc[nt][r]);
          if (needmask) {
            const int kg = k0 + nt * 16 + qd * 4 + r;  // key index
            const int qg = qr + lq;                    // query index
            pv = (kg > qg) ? 0.f : pv;
          }
          ap_prev[nt >> 1][((nt & 1) << 2) | r] = (bf16_t)pv;
        }
      vprev = vcur;
      vcur = vnext;
      cb ^= 1;
    }
    // epilogue: PV of the segment's last tile
    do_pv(Vt[vprev]);

    // normalize + store: osum[r] = rs for q-row qd*4+r (all cols equal) --
    // exactly the C-layout rows this lane writes. No shuffles needed.
    float rinv[4];
#pragma unroll
    for (int r = 0; r < 4; ++r) rinv[r] = 1.0f / osum[r];
#pragma unroll
    for (int nt = 0; nt < 4; ++nt)
#pragma unroll
      for (int r = 0; r < 4; ++r) {
        const int qg = qr + qd * 4 + r;
        O[(rowbase + qg) * E + h * 64 + nt * 16 + lq] =
            (bf16_t)(oacc[nt][r] * rinv[r]);
      }
  }
}

// ---------------------------------------------------------------------------
// launch
// ---------------------------------------------------------------------------
extern "C" void kernel_launch(void* const* d_in, const int* in_sizes, int n_in,
                              void* d_out, int out_size, void* d_ws, size_t ws_size,
                              hipStream_t stream) {
  const float* x  = (const float*)d_in[0];
  const float* Wq = (const float*)d_in[1];
  const float* bq = (const float*)d_in[2];
  const float* Wk = (const float*)d_in[3];
  const float* bk = (const float*)d_in[4];
  const float* Wv = (const float*)d_in[5];
  const float* bv = (const float*)d_in[6];
  const float* Wo = (const float*)d_in[7];
  const float* bo = (const float*)d_in[8];
  float* out = (float*)d_out;

  unsigned char* ws = (unsigned char*)d_ws;
  constexpr size_t MB = 1ull << 20;
  bf16_t* xb  = (bf16_t*)(ws + 0 * MB);   // 8 MB; reused as Ob after qkv
  bf16_t* wqb = (bf16_t*)(ws + 8 * MB);   // wq/wk/wv contiguous [3072][1024]
  bf16_t* wkb = (bf16_t*)(ws + 10 * MB);
  bf16_t* wvb = (bf16_t*)(ws + 12 * MB);
  bf16_t* wob = (bf16_t*)(ws + 14 * MB);
  bf16_t* Qb  = (bf16_t*)(ws + 16 * MB);  // Q/K/V contiguous [3][4096][1024]
  bf16_t* Kb  = (bf16_t*)(ws + 24 * MB);
  bf16_t* Vb  = (bf16_t*)(ws + 32 * MB);  // row-major V; dead after vtrans
  bf16_t* VT  = (bf16_t*)(ws + 40 * MB);  // [32 bh][64 d][2048 s, sigma-perm per 64]
  bf16_t* Ob  = xb;                       // xb dead after qkv

  cvt_all_kernel<<<4096 + 4 * 1024, 256, 0, stream>>>(
      x, Wq, Wk, Wv, Wo, xb, wqb, wkb, wvb, wob);

  qkv8_kernel<<<256, 512, 0, stream>>>(xb, wqb, bq, bk, bv, Qb);

  vtrans_kernel<<<dim3(32, 32), 256, 0, stream>>>(Vb, VT);

  attn_kernel<<<512, 256, 0, stream>>>(Qb, Kb, VT, Ob);

  oproj_gemm_kernel<<<dim3(8, 64), 256, 0, stream>>>(Ob, wob, bo, out);
}

// Round 4
// 174.455 us; speedup vs baseline: 1.1967x; 1.0354x over previous
//
#include <hip/hip_runtime.h>
#include <hip/hip_bf16.h>

typedef __bf16 bf16_t;
typedef __bf16 bf16x8 __attribute__((ext_vector_type(8)));
typedef __bf16 bf16x4 __attribute__((ext_vector_type(4)));
typedef float  f32x4  __attribute__((ext_vector_type(4)));

#define MFMA16(a, b, c) __builtin_amdgcn_mfma_f32_16x16x32_bf16((a), (b), (c), 0, 0, 0)

constexpr int E  = 1024;
constexpr int S  = 2048;
constexpr int H  = 16;
constexpr int M  = 4096;  // B*S

// ---------------------------------------------------------------------------
// async global->LDS 16B (wave-uniform LDS base + lane*16)
// ---------------------------------------------------------------------------
__device__ __forceinline__ void glds16(const bf16_t* src, bf16_t* dst) {
  __builtin_amdgcn_global_load_lds(
      (const __attribute__((address_space(1))) void*)src,
      (__attribute__((address_space(3))) void*)dst, 16, 0, 0);
}

// Stage a [ROWS x 64] bf16 tile (global row stride gld) into LDS, XOR-swizzled.
// NT = block threads.
template <int ROWS, int NT>
__device__ __forceinline__ void stage_tile(const bf16_t* g, int gld,
                                           bf16_t* lds, int tid) {
  const int w = tid >> 6, l = tid & 63;
#pragma unroll
  for (int i = 0; i < ROWS * 8 / NT; ++i) {
    const int c = i * NT + w * 64 + l;
    const int row = c >> 3;
    const int gch = (c & 7) ^ (row & 7);
    glds16(g + (size_t)row * gld + gch * 8, lds + (size_t)(i * NT + w * 64) * 8);
  }
}

// Read an 8-elem k-chunk (kc in [0,8)) of row `row` from a swizzled tile.
__device__ __forceinline__ bf16x8 read_frag(const bf16_t* lds, int row, int kc) {
  return *(const bf16x8*)(lds + (size_t)((row << 3) + (kc ^ (row & 7))) * 8);
}

// ---------------------------------------------------------------------------
// fused fp32->bf16 conversion for x + 4 weight matrices
// ---------------------------------------------------------------------------
__global__ void cvt_all_kernel(const float* __restrict__ x,
                               const float* __restrict__ w0, const float* __restrict__ w1,
                               const float* __restrict__ w2, const float* __restrict__ w3,
                               bf16_t* __restrict__ xb,
                               bf16_t* __restrict__ o0, bf16_t* __restrict__ o1,
                               bf16_t* __restrict__ o2, bf16_t* __restrict__ o3) {
  const int bid = blockIdx.x;
  const float* s;
  bf16_t* d;
  int idx;
  if (bid < 4096) {
    s = x; d = xb; idx = bid * 256 + threadIdx.x;
  } else {
    const int seg = (bid - 4096) >> 10;
    s = seg == 0 ? w0 : seg == 1 ? w1 : seg == 2 ? w2 : w3;
    d = seg == 0 ? o0 : seg == 1 ? o1 : seg == 2 ? o2 : o3;
    idx = ((bid - 4096) & 1023) * 256 + threadIdx.x;
  }
  float4 v = ((const float4*)s)[idx];
  bf16x4 o;
  o[0] = (bf16_t)v.x; o[1] = (bf16_t)v.y; o[2] = (bf16_t)v.z; o[3] = (bf16_t)v.w;
  ((bf16x4*)d)[idx] = o;
}

// ---------------------------------------------------------------------------
// fused QKV projection, v3: 256x192 tile, BK=64, 512 thr (8 waves = 2M x 4N),
// double-buffered LDS (112 KB), ONE barrier per K-tile (m97-style free
// scheduling: compiler interleaves 22 ds_read + 48 MFMA with fine lgkmcnt).
// All 7 DMA loads for tile g+1 issued at the TOP of tile g's compute ->
// ~full-tile latency to land (mostly L2-hit); the __syncthreads drain at
// tile end waits only the residue.
//
// v3 vs v2 (42.7 us, MfmaUtil 23.5%): killed 7 of 8 barriers/K-tile (the
// per-phase lockstep serialized LDS bursts against MFMA bursts), kk-major
// full-width fragment reads (B-frags read once, 22 reads vs 28).
//
// W fused [3072][1024]; Q/K outputs row-major [4096][1024] at QKb; the V
// third is written DIRECTLY into VT's sigma-permuted transposed layout
// (vtrans kernel deleted). Q PRE-SCALED by log2(e)/8.
// Grid 256 = 1 block/CU, 4x4-region XCD swizzle.
// ---------------------------------------------------------------------------
__global__ __launch_bounds__(512, 2) void qkv8_kernel(
    const bf16_t* __restrict__ xb, const bf16_t* __restrict__ W3,
    const float* __restrict__ bq, const float* __restrict__ bk,
    const float* __restrict__ bv, bf16_t* __restrict__ QKb,
    bf16_t* __restrict__ VT) {
  __shared__ __align__(16) bf16_t As[2][256 * 64];  // 64 KB
  __shared__ __align__(16) bf16_t Bs[2][192 * 64];  // 48 KB
  const int tid = threadIdx.x;
  const int l = tid & 63, lq = l & 15, qd = l >> 4;
  const int w = tid >> 6, wm = w >> 2, wn = w & 3;

  // XCD-aware 4x4-region swizzle: xcd k owns regions {2k, 2k+1}
  const int wg = blockIdx.x;
  const int xcd = wg & 7, i5 = wg >> 3;        // i5 in [0,32)
  const int region = xcd * 2 + (i5 >> 4);      // [0,16), 4x4 block regions
  const int j = i5 & 15;
  const int bx = (region & 3) * 4 + (j & 3);   // n-tile [0,16)
  const int by = (region >> 2) * 4 + (j >> 2); // m-tile [0,16)
  const int m0 = by * 256, n0 = bx * 192;

  const bf16_t* Ag = xb + (size_t)m0 * E;
  const bf16_t* Bg = W3 + (size_t)n0 * E;

  f32x4 acc[8][3];
#pragma unroll
  for (int mi = 0; mi < 8; ++mi)
#pragma unroll
    for (int n = 0; n < 3; ++n) acc[mi][n] = (f32x4){0.f, 0.f, 0.f, 0.f};

  // prologue: stage K-tile 0 into slot 0 (syncthreads drains vmcnt)
  stage_tile<256, 512>(Ag, E, As[0], tid);
  stage_tile<192, 512>(Bg, E, Bs[0], tid);
  __syncthreads();

#pragma unroll 1
  for (int g = 0; g < 16; ++g) {
    const int s = g & 1;
    const bf16_t* Al = As[s];
    const bf16_t* Bl = Bs[s];
    // issue next tile's DMA first: maximum latency cover (~whole tile body)
    if (g < 15) {
      stage_tile<256, 512>(Ag + (g + 1) * 64, E, As[s ^ 1], tid);
      stage_tile<192, 512>(Bg + (g + 1) * 64, E, Bs[s ^ 1], tid);
    }
    // free-scheduled compute: compiler interleaves ds_read/MFMA (fine lgkmcnt)
#pragma unroll
    for (int kk = 0; kk < 2; ++kk) {
      bf16x8 af[8], bfr[3];
#pragma unroll
      for (int jj = 0; jj < 8; ++jj)
        af[jj] = read_frag(Al, wm * 128 + jj * 16 + lq, kk * 4 + qd);
#pragma unroll
      for (int n = 0; n < 3; ++n)
        bfr[n] = read_frag(Bl, wn * 48 + n * 16 + lq, kk * 4 + qd);
#pragma unroll
      for (int jj = 0; jj < 8; ++jj)
#pragma unroll
        for (int n = 0; n < 3; ++n)
          acc[jj][n] = MFMA16(af[jj], bfr[n], acc[jj][n]);
    }
    // one barrier per K-tile: drains DMA (tile g+1 ready) AND guarantees all
    // waves' reads of slot s are done before tile g+2's DMA overwrites it.
    __syncthreads();
  }

  // epilogue: bias (+ Q scale); Q/K row-major, V straight into VT
  // (sigma-permuted transpose: VT[(bh*64+d)*S + s0 + p], p = inv_sigma(sl),
  //  inv_sigma: sl = a*16+bb*4+cc -> p = (a>>1)*32 + bb*8 + (a&1)*4 + cc;
  //  the 4 r-rows share a,bb and map to 4 consecutive p -> one bf16x4 store)
#pragma unroll
  for (int n = 0; n < 3; ++n) {
    const int col = n0 + wn * 48 + n * 16 + lq;
    const int mat = col >> 10, cc = col & 1023;
    const float bvv = (mat == 0 ? bq : mat == 1 ? bk : bv)[cc];
    if (mat < 2) {
      const float sc = (mat == 0) ? 0.18033688011112043f : 1.0f;  // log2(e)/8
      bf16_t* Out = QKb + (size_t)mat * ((size_t)M * E);
#pragma unroll
      for (int mi = 0; mi < 8; ++mi)
#pragma unroll
        for (int r = 0; r < 4; ++r) {
          const int row = m0 + wm * 128 + mi * 16 + qd * 4 + r;
          Out[(size_t)row * E + cc] = (bf16_t)((acc[mi][n][r] + bvv) * sc);
        }
    } else {
      const int d = cc & 63, hh = cc >> 6;
#pragma unroll
      for (int mi = 0; mi < 8; ++mi) {
        const int row = m0 + wm * 128 + mi * 16 + qd * 4;  // r=0 base
        const int bb_ = row >> 11;          // batch
        const int s_loc = row & (S - 1);
        const int sl = s_loc & 63, s0 = s_loc & ~63;
        const int a = sl >> 4, b4 = (sl >> 2) & 3;
        const int pb = (a >> 1) * 32 + b4 * 8 + (a & 1) * 4;
        bf16x4 vv;
#pragma unroll
        for (int r = 0; r < 4; ++r) vv[r] = (bf16_t)(acc[mi][n][r] + bvv);
        *(bf16x4*)&VT[((size_t)((bb_ * 16 + hh) * 64 + d)) * S + s0 + pb] = vv;
      }
    }
  }
}

// ---------------------------------------------------------------------------
// output projection: 64x128 tiles -> grid (8, 64) = 512 blocks.
// ---------------------------------------------------------------------------
__global__ __launch_bounds__(256) void oproj_gemm_kernel(
    const bf16_t* __restrict__ Ob, const bf16_t* __restrict__ wo,
    const float* __restrict__ bo, float* __restrict__ out) {
  __shared__ __align__(16) bf16_t As[64 * 64];    // 8 KB
  __shared__ __align__(16) bf16_t Bs[128 * 64];   // 16 KB
  const int tid = threadIdx.x;
  const int n0 = blockIdx.x * 128;
  const int m0 = blockIdx.y * 64;
  const int w = tid >> 6, l = tid & 63, lq = l & 15, qd = l >> 4;
  const int wr = (w >> 1) * 32, wc = (w & 1) * 64;

  f32x4 acc[2][4];
#pragma unroll
  for (int i = 0; i < 2; ++i)
#pragma unroll
    for (int j = 0; j < 4; ++j) acc[i][j] = (f32x4){0.f, 0.f, 0.f, 0.f};

  for (int kt = 0; kt < 16; ++kt) {
    __syncthreads();
    stage_tile<64, 256>(Ob + (size_t)m0 * E + kt * 64, E, As, tid);
    stage_tile<128, 256>(wo + (size_t)n0 * E + kt * 64, E, Bs, tid);
    __syncthreads();
#pragma unroll
    for (int ks = 0; ks < 2; ++ks) {
      bf16x8 af[2], bw[4];
#pragma unroll
      for (int mi = 0; mi < 2; ++mi)
        af[mi] = read_frag(As, wr + mi * 16 + lq, ks * 4 + qd);
#pragma unroll
      for (int ni = 0; ni < 4; ++ni)
        bw[ni] = read_frag(Bs, wc + ni * 16 + lq, ks * 4 + qd);
#pragma unroll
      for (int mi = 0; mi < 2; ++mi)
#pragma unroll
        for (int ni = 0; ni < 4; ++ni)
          acc[mi][ni] = MFMA16(af[mi], bw[ni], acc[mi][ni]);
    }
  }
#pragma unroll
  for (int ni = 0; ni < 4; ++ni) {
    const int col = n0 + wc + ni * 16 + lq;
    const float bvv = bo[col];
#pragma unroll
    for (int mi = 0; mi < 2; ++mi)
#pragma unroll
      for (int r = 0; r < 4; ++r) {
        const int row = m0 + wr + mi * 16 + qd * 4 + r;
        out[(size_t)row * E + col] = acc[mi][ni][r] + bvv;
      }
  }
}

// ---------------------------------------------------------------------------
// causal flash attention v13: operand-swapped S^T = K*Q^T (softmax'd regs ARE
// the PV A-fragment; keys sigma-permuted in VT; P never touches LDS).
//  * T15 PIPELINE: PV of tile kt-1 executes during iteration kt, overlapping
//    the softmax VALU of tile kt. V TRIPLE-buffered (40 KB LDS, 2 blocks/CU).
//  * ROW-SUM VIA MFMA: rs = P x ones; output layout row=qd*4+r is exactly
//    the O-write layout (no shuffles; error cancels with bf16-rounded P).
//  * __builtin_amdgcn_exp2f; setprio(1) around QK+PV MFMA cluster.
// Uniform work: block = q-tile pair {31-p, p} = 33 k-tiles. 512 blocks x
// 256 thr = 2 blocks/CU, 8 waves/CU sustained. No-max softmax (Q pre-scaled
// by log2e/8). XCD-clustered mapping: g=bid&7 -> bh in [4g,4g+4).
// ---------------------------------------------------------------------------
__global__ __launch_bounds__(256, 2) void attn_kernel(
    const bf16_t* __restrict__ Q, const bf16_t* __restrict__ K,
    const bf16_t* __restrict__ VT, bf16_t* __restrict__ O) {
  __shared__ __align__(16) bf16_t Ks[2][64 * 64];  // K dbuf, swizzled [key][d]
  __shared__ __align__(16) bf16_t Vt[3][64 * 64];  // V tri-buf, swizzled [d][perm-key]

  const int tid = threadIdx.x;
  const int w = tid >> 6, l = tid & 63;
  const int lq = l & 15, qd = l >> 4;
  const int bid = blockIdx.x;
  const int g = bid & 7, t = bid >> 3;  // 64 blocks per XCD-group
  const int bh = g * 4 + (t & 3);       // 4 bh per XCD-group: L2-resident K/VT
  const int p = t >> 2;                 // pair index: q-tiles {31-p, p}
  const int b = bh >> 4, h = bh & 15;
  const size_t rowbase = (size_t)b * S;
  const bf16_t* Kg = K + rowbase * E + h * 64;
  const bf16_t* Vg = VT + (size_t)bh * 64 * S;

  // constant all-ones B-fragment for the row-sum MFMA
  bf16x8 ones;
#pragma unroll
  for (int j = 0; j < 8; ++j) ones[j] = (bf16_t)1.0f;

  // prefetch k-tile 0 into K slot 0 / V slot 0
  stage_tile<64, 256>(Kg, E, Ks[0], tid);
  stage_tile<64, 256>(Vg, S, Vt[0], tid);
  int cb = 0;    // K slot of current tile
  int vcur = 0;  // V slot of current tile

#pragma unroll 1
  for (int seg = 0; seg < 2; ++seg) {
    const int qt = seg ? p : 31 - p;    // heavy q-tile first
    const int qr = qt * 64 + w * 16;    // wave rows [qr, qr+16)

    // Q fragments (pre-scaled), used as the MFMA B-operand: rows qr+lq
    bf16x8 aq[2];
#pragma unroll
    for (int ks = 0; ks < 2; ++ks)
      aq[ks] = *(const bf16x8*)(Q + (rowbase + qr + lq) * E + h * 64 +
                                ks * 32 + qd * 8);

    f32x4 oacc[4];
#pragma unroll
    for (int nt = 0; nt < 4; ++nt) oacc[nt] = (f32x4){0.f, 0.f, 0.f, 0.f};
    f32x4 osum = (f32x4){0.f, 0.f, 0.f, 0.f};  // row sums via ones-MFMA
    bf16x8 ap_prev[2];                          // P frags of tile kt-1
    int vprev = vcur;

    // PV of the previous tile from V slot vp (reads ap_prev; accumulates
    // oacc + osum). Issued right after QK so its MFMAs overlap softmax VALU.
    auto do_pv = [&](const bf16_t* Vp) {
#pragma unroll
      for (int ks = 0; ks < 2; ++ks) {
        bf16x8 bv[4];
#pragma unroll
        for (int nt = 0; nt < 4; ++nt)
          bv[nt] = read_frag(Vp, nt * 16 + lq, ks * 4 + qd);
#pragma unroll
        for (int nt = 0; nt < 4; ++nt)
          oacc[nt] = MFMA16(ap_prev[ks], bv[nt], oacc[nt]);
        osum = MFMA16(ap_prev[ks], ones, osum);
      }
    };

    for (int kt = 0; kt <= qt; ++kt) {
      __syncthreads();  // own vmcnt(0) drains DMA into K[cb]/V[vcur]; all
                        // waves' reads of the slots being rewritten are done
      const int vnext = (vcur + 1 == 3) ? 0 : vcur + 1;
      if (kt < qt) {    // stage tile kt+1
        const int kn = (kt + 1) * 64;
        stage_tile<64, 256>(Kg + (size_t)kn * E, E, Ks[cb ^ 1], tid);
        stage_tile<64, 256>(Vg + kn, S, Vt[vnext], tid);
      } else if (seg == 0) {  // last A-iter: prefetch segment B's tile 0
        stage_tile<64, 256>(Kg, E, Ks[cb ^ 1], tid);
        stage_tile<64, 256>(Vg, S, Vt[vnext], tid);
      }
      const bf16_t* Kc = Ks[cb];
      const int k0 = kt * 64;
      const bool needmask = (kt == qt);  // exact: kt<qt => k0+63 < qr

      // ---- S^T = K * Q^T : 8 MFMA; lane holds q=lq, keys nt*16+qd*4+r ----
      f32x4 sacc[4];
#pragma unroll
      for (int nt = 0; nt < 4; ++nt) sacc[nt] = (f32x4){0.f, 0.f, 0.f, 0.f};
      __builtin_amdgcn_s_setprio(1);
#pragma unroll
      for (int ks = 0; ks < 2; ++ks) {
        bf16x8 bk[4];
#pragma unroll
        for (int nt = 0; nt < 4; ++nt)
          bk[nt] = read_frag(Kc, nt * 16 + lq, ks * 4 + qd);
#pragma unroll
        for (int nt = 0; nt < 4; ++nt)
          sacc[nt] = MFMA16(bk[nt], aq[ks], sacc[nt]);
      }
      // ---- PV of tile kt-1 (independent of softmax below; overlaps it) ----
      if (kt > 0) do_pv(Vt[vprev]);
      __builtin_amdgcn_s_setprio(0);

      // ---- softmax in registers; pack directly into next PV A-frags ----
      // ap[ks][j] = pv(nt = ks*2 + (j>>2), r = j&3)  [matches VT's sigma]
#pragma unroll
      for (int nt = 0; nt < 4; ++nt)
#pragma unroll
        for (int r = 0; r < 4; ++r) {
          float pv = __builtin_amdgcn_exp2f(sacc[nt][r]);
          if (needmask) {
            const int kg = k0 + nt * 16 + qd * 4 + r;  // key index
            const int qg = qr + lq;                    // query index
            pv = (kg > qg) ? 0.f : pv;
          }
          ap_prev[nt >> 1][((nt & 1) << 2) | r] = (bf16_t)pv;
        }
      vprev = vcur;
      vcur = vnext;
      cb ^= 1;
    }
    // epilogue: PV of the segment's last tile
    do_pv(Vt[vprev]);

    // normalize + store: osum[r] = rs for q-row qd*4+r (all cols equal) --
    // exactly the C-layout rows this lane writes. No shuffles needed.
    float rinv[4];
#pragma unroll
    for (int r = 0; r < 4; ++r) rinv[r] = 1.0f / osum[r];
#pragma unroll
    for (int nt = 0; nt < 4; ++nt)
#pragma unroll
      for (int r = 0; r < 4; ++r) {
        const int qg = qr + qd * 4 + r;
        O[(rowbase + qg) * E + h * 64 + nt * 16 + lq] =
            (bf16_t)(oacc[nt][r] * rinv[r]);
      }
  }
}

// ---------------------------------------------------------------------------
// launch
// ---------------------------------------------------------------------------
extern "C" void kernel_launch(void* const* d_in, const int* in_sizes, int n_in,
                              void* d_out, int out_size, void* d_ws, size_t ws_size,
                              hipStream_t stream) {
  const float* x  = (const float*)d_in[0];
  const float* Wq = (const float*)d_in[1];
  const float* bq = (const float*)d_in[2];
  const float* Wk = (const float*)d_in[3];
  const float* bk = (const float*)d_in[4];
  const float* Wv = (const float*)d_in[5];
  const float* bv = (const float*)d_in[6];
  const float* Wo = (const float*)d_in[7];
  const float* bo = (const float*)d_in[8];
  float* out = (float*)d_out;

  unsigned char* ws = (unsigned char*)d_ws;
  constexpr size_t MB = 1ull << 20;
  bf16_t* xb  = (bf16_t*)(ws + 0 * MB);   // 8 MB; reused as Ob after qkv
  bf16_t* wqb = (bf16_t*)(ws + 8 * MB);   // wq/wk/wv contiguous [3072][1024]
  bf16_t* wkb = (bf16_t*)(ws + 10 * MB);
  bf16_t* wvb = (bf16_t*)(ws + 12 * MB);
  bf16_t* wob = (bf16_t*)(ws + 14 * MB);
  bf16_t* Qb  = (bf16_t*)(ws + 16 * MB);  // Q/K contiguous [2][4096][1024]
  bf16_t* VT  = (bf16_t*)(ws + 40 * MB);  // [32 bh][64 d][2048 s, sigma-perm per 64]
  bf16_t* Ob  = xb;                       // xb dead after qkv

  cvt_all_kernel<<<4096 + 4 * 1024, 256, 0, stream>>>(
      x, Wq, Wk, Wv, Wo, xb, wqb, wkb, wvb, wob);

  qkv8_kernel<<<256, 512, 0, stream>>>(xb, wqb, bq, bk, bv, Qb, VT);

  attn_kernel<<<512, 256, 0, stream>>>(Qb, Qb + (size_t)M * E, VT, Ob);

  oproj_gemm_kernel<<<dim3(8, 64), 256, 0, stream>>>(Ob, wob, bo, out);
}

// Round 5
// 174.087 us; speedup vs baseline: 1.1992x; 1.0021x over previous
//
#include <hip/hip_runtime.h>
#include <hip/hip_bf16.h>

typedef __bf16 bf16_t;
typedef __bf16 bf16x8 __attribute__((ext_vector_type(8)));
typedef __bf16 bf16x4 __attribute__((ext_vector_type(4)));
typedef float  f32x4  __attribute__((ext_vector_type(4)));

#define MFMA16(a, b, c) __builtin_amdgcn_mfma_f32_16x16x32_bf16((a), (b), (c), 0, 0, 0)

constexpr int E  = 1024;
constexpr int S  = 2048;
constexpr int H  = 16;
constexpr int M  = 4096;  // B*S

// ---------------------------------------------------------------------------
// async global->LDS 16B (wave-uniform LDS base + lane*16)
// ---------------------------------------------------------------------------
__device__ __forceinline__ void glds16(const bf16_t* src, bf16_t* dst) {
  __builtin_amdgcn_global_load_lds(
      (const __attribute__((address_space(1))) void*)src,
      (__attribute__((address_space(3))) void*)dst, 16, 0, 0);
}

// Stage a [ROWS x 64] bf16 tile (global row stride gld) into LDS, XOR-swizzled.
// NT = block threads.
template <int ROWS, int NT>
__device__ __forceinline__ void stage_tile(const bf16_t* g, int gld,
                                           bf16_t* lds, int tid) {
  const int w = tid >> 6, l = tid & 63;
#pragma unroll
  for (int i = 0; i < ROWS * 8 / NT; ++i) {
    const int c = i * NT + w * 64 + l;
    const int row = c >> 3;
    const int gch = (c & 7) ^ (row & 7);
    glds16(g + (size_t)row * gld + gch * 8, lds + (size_t)(i * NT + w * 64) * 8);
  }
}

// Stage interleaved A-chunk c of a 256-row tile: LDS rows
// {h*128 + c*64 + rr : h in {0,1}, rr in [0,64)} (2 glds/thread @512 thr).
// Phase (kk, jjh=c) then reads rows wm*128 + (c*4+jj)*16+lq for BOTH wm.
__device__ __forceinline__ void stage_A_chunk(const bf16_t* g, int c,
                                              bf16_t* lds, int tid) {
  const int w = tid >> 6, l = tid & 63;
#pragma unroll
  for (int i = 0; i < 2; ++i) {
    const int gc = i * 512 + w * 64 + l;      // [0,1024)
    const int row_l = gc >> 3;                // [0,128)
    const int col8 = gc & 7;
    const int h = row_l >> 6, rr = row_l & 63;
    const int row = h * 128 + c * 64 + rr;    // LDS == global row
    const int gch = col8 ^ (row & 7);
    glds16(g + (size_t)row * E + gch * 8, lds + ((size_t)row * 8 + col8) * 8);
  }
}

// Read an 8-elem k-chunk (kc in [0,8)) of row `row` from a swizzled tile.
__device__ __forceinline__ bf16x8 read_frag(const bf16_t* lds, int row, int kc) {
  return *(const bf16x8*)(lds + (size_t)((row << 3) + (kc ^ (row & 7))) * 8);
}

// ---------------------------------------------------------------------------
// fused fp32->bf16 conversion for x + 4 weight matrices
// ---------------------------------------------------------------------------
__global__ void cvt_all_kernel(const float* __restrict__ x,
                               const float* __restrict__ w0, const float* __restrict__ w1,
                               const float* __restrict__ w2, const float* __restrict__ w3,
                               bf16_t* __restrict__ xb,
                               bf16_t* __restrict__ o0, bf16_t* __restrict__ o1,
                               bf16_t* __restrict__ o2, bf16_t* __restrict__ o3) {
  const int bid = blockIdx.x;
  const float* s;
  bf16_t* d;
  int idx;
  if (bid < 4096) {
    s = x; d = xb; idx = bid * 256 + threadIdx.x;
  } else {
    const int seg = (bid - 4096) >> 10;
    s = seg == 0 ? w0 : seg == 1 ? w1 : seg == 2 ? w2 : w3;
    d = seg == 0 ? o0 : seg == 1 ? o1 : seg == 2 ? o2 : o3;
    idx = ((bid - 4096) & 1023) * 256 + threadIdx.x;
  }
  float4 v = ((const float4*)s)[idx];
  bf16x4 o;
  o[0] = (bf16_t)v.x; o[1] = (bf16_t)v.y; o[2] = (bf16_t)v.z; o[3] = (bf16_t)v.w;
  ((bf16x4*)d)[idx] = o;
}

// ---------------------------------------------------------------------------
// fused QKV projection, v4: m201-style 256x256 8-phase port.
// 512 thr = 8 waves (2M x 4N), wave tile 128x64, acc 8x4 f32x4.
// LDS 128 KB: As[2][256x64] + Bs[2][256x64], XOR-swizzled (T2).
// 4 phases per K-tile (kk, jjh); each phase: {4-8 ds_read_b128; issue ONE
// staging chunk of tile t+1; s_barrier; lgkmcnt(0)+sched_barrier; setprio(1);
// 16 MFMA; setprio(0); [counted vmcnt]; s_barrier}.
// Staging chunks per K-tile (2 glds/thread each): ph0->Bc0 (B rows 0-127),
// ph1->Bc1 (128-255), ph2->Ac0 (interleaved {0-63}u{128-191}), ph3->Ac1.
// Counted vmcnt (T4, never 0 mid-loop):
//   end-ph3: vmcnt(2)  -> tile t+1's Bc0,Bc1,Ac0 landed (Ac1 may fly)
//   end-ph0: vmcnt(2)  -> Ac1(t) landed for ph1 (Bc0(t+1) may fly)
// Per-wave vmcnt + following s_barrier = block-wide completion guarantee.
// Grid 192 (16m x 12n) = 75% of CUs, 1 block/CU; XCD swizzle: 24 blocks/XCD
// sharing 2 A-panels. Each 256-col tile lies in ONE of Q/K/V: per-block
// uniform routing; V-tiles write straight into sigma-permuted VT.
// Q PRE-SCALED by log2(e)/8.
// ---------------------------------------------------------------------------
__global__ __launch_bounds__(512, 1) void qkv8_kernel(
    const bf16_t* __restrict__ xb, const bf16_t* __restrict__ W3,
    const float* __restrict__ bq, const float* __restrict__ bk,
    const float* __restrict__ bv, bf16_t* __restrict__ QKb,
    bf16_t* __restrict__ VT) {
  __shared__ __align__(16) bf16_t As[2][256 * 64];  // 64 KB
  __shared__ __align__(16) bf16_t Bs[2][256 * 64];  // 64 KB
  const int tid = threadIdx.x;
  const int l = tid & 63, lq = l & 15, qd = l >> 4;
  const int w = tid >> 6, wm = w >> 2, wn = w & 3;

  // XCD swizzle: 192 blocks, XCD k gets swz [24k, 24k+24) = 2 m-rows x 12
  const int swz = (blockIdx.x & 7) * 24 + (blockIdx.x >> 3);
  const int by = swz / 12, bx = swz % 12;
  const int m0 = by * 256, n0 = bx * 256;

  const bf16_t* Ag = xb + (size_t)m0 * E;
  const bf16_t* Bg = W3 + (size_t)n0 * E;

  f32x4 acc[8][4];
#pragma unroll
  for (int jj = 0; jj < 8; ++jj)
#pragma unroll
    for (int n = 0; n < 4; ++n) acc[jj][n] = (f32x4){0.f, 0.f, 0.f, 0.f};

  // prologue: stage tile 0 (issue order Bc0, Bc1, Ac0, Ac1 = steady state)
  stage_tile<128, 512>(Bg, E, Bs[0], tid);
  stage_tile<128, 512>(Bg + (size_t)128 * E, E, Bs[0] + 128 * 64, tid);
  stage_A_chunk(Ag, 0, As[0], tid);
  stage_A_chunk(Ag, 1, As[0], tid);
  asm volatile("s_waitcnt vmcnt(2)" ::: "memory");
  __builtin_amdgcn_s_barrier();

#pragma unroll 1
  for (int g = 0; g < 16; ++g) {
    const int s = g & 1;
    const bf16_t* Al = As[s];
    const bf16_t* Bl = Bs[s];
    bf16_t* An = As[s ^ 1];
    bf16_t* Bn = Bs[s ^ 1];
    const bf16_t* Agn = Ag + (g + 1) * 64;
    const bf16_t* Bgn = Bg + (g + 1) * 64;
    const bool more = (g < 15);
    bf16x8 af[4], bfr[4];

    // ---------------- ph0: kk=0, jj 0-3 (+ all B kk0) ----------------
#pragma unroll
    for (int jj = 0; jj < 4; ++jj)
      af[jj] = read_frag(Al, wm * 128 + jj * 16 + lq, qd);
#pragma unroll
    for (int n = 0; n < 4; ++n)
      bfr[n] = read_frag(Bl, wn * 64 + n * 16 + lq, qd);
    if (more) stage_tile<128, 512>(Bgn, E, Bn, tid);
    __builtin_amdgcn_s_barrier();
    asm volatile("s_waitcnt lgkmcnt(0)" ::: "memory");
    __builtin_amdgcn_sched_barrier(0);
    __builtin_amdgcn_s_setprio(1);
#pragma unroll
    for (int jj = 0; jj < 4; ++jj)
#pragma unroll
      for (int n = 0; n < 4; ++n)
        acc[jj][n] = MFMA16(af[jj], bfr[n], acc[jj][n]);
    __builtin_amdgcn_s_setprio(0);
    if (more) asm volatile("s_waitcnt vmcnt(2)" ::: "memory");
    else      asm volatile("s_waitcnt vmcnt(0)" ::: "memory");
    __builtin_amdgcn_s_barrier();

    // ---------------- ph1: kk=0, jj 4-7 (reuse B kk0 frags) ----------------
#pragma unroll
    for (int jj = 0; jj < 4; ++jj)
      af[jj] = read_frag(Al, wm * 128 + (4 + jj) * 16 + lq, qd);
    if (more) stage_tile<128, 512>(Bgn + (size_t)128 * E, E, Bn + 128 * 64, tid);
    __builtin_amdgcn_s_barrier();
    asm volatile("s_waitcnt lgkmcnt(0)" ::: "memory");
    __builtin_amdgcn_sched_barrier(0);
    __builtin_amdgcn_s_setprio(1);
#pragma unroll
    for (int jj = 0; jj < 4; ++jj)
#pragma unroll
      for (int n = 0; n < 4; ++n)
        acc[4 + jj][n] = MFMA16(af[jj], bfr[n], acc[4 + jj][n]);
    __builtin_amdgcn_s_setprio(0);
    __builtin_amdgcn_s_barrier();

    // ---------------- ph2: kk=1, jj 0-3 (+ all B kk1) ----------------
#pragma unroll
    for (int jj = 0; jj < 4; ++jj)
      af[jj] = read_frag(Al, wm * 128 + jj * 16 + lq, 4 + qd);
#pragma unroll
    for (int n = 0; n < 4; ++n)
      bfr[n] = read_frag(Bl, wn * 64 + n * 16 + lq, 4 + qd);
    if (more) stage_A_chunk(Agn, 0, An, tid);
    __builtin_amdgcn_s_barrier();
    asm volatile("s_waitcnt lgkmcnt(0)" ::: "memory");
    __builtin_amdgcn_sched_barrier(0);
    __builtin_amdgcn_s_setprio(1);
#pragma unroll
    for (int jj = 0; jj < 4; ++jj)
#pragma unroll
      for (int n = 0; n < 4; ++n)
        acc[jj][n] = MFMA16(af[jj], bfr[n], acc[jj][n]);
    __builtin_amdgcn_s_setprio(0);
    __builtin_amdgcn_s_barrier();

    // ---------------- ph3: kk=1, jj 4-7 ----------------
#pragma unroll
    for (int jj = 0; jj < 4; ++jj)
      af[jj] = read_frag(Al, wm * 128 + (4 + jj) * 16 + lq, 4 + qd);
    if (more) stage_A_chunk(Agn, 1, An, tid);
    __builtin_amdgcn_s_barrier();
    asm volatile("s_waitcnt lgkmcnt(0)" ::: "memory");
    __builtin_amdgcn_sched_barrier(0);
    __builtin_amdgcn_s_setprio(1);
#pragma unroll
    for (int jj = 0; jj < 4; ++jj)
#pragma unroll
      for (int n = 0; n < 4; ++n)
        acc[4 + jj][n] = MFMA16(af[jj], bfr[n], acc[4 + jj][n]);
    __builtin_amdgcn_s_setprio(0);
    if (more) asm volatile("s_waitcnt vmcnt(2)" ::: "memory");
    __builtin_amdgcn_s_barrier();
  }

  // epilogue: per-block uniform matrix routing (256-col tile in one matrix)
  const int mat = n0 >> 10;            // 0=Q, 1=K, 2=V
  const int ccb = n0 & 1023;
  const float* bp = (mat == 0) ? bq : (mat == 1) ? bk : bv;
  if (mat < 2) {
    const float sc = (mat == 0) ? 0.18033688011112043f : 1.0f;  // log2(e)/8
    bf16_t* Out = QKb + (size_t)mat * ((size_t)M * E);
#pragma unroll
    for (int n = 0; n < 4; ++n) {
      const int cc = ccb + wn * 64 + n * 16 + lq;
      const float bvv = bp[cc];
#pragma unroll
      for (int jj = 0; jj < 8; ++jj)
#pragma unroll
        for (int r = 0; r < 4; ++r) {
          const int row = m0 + wm * 128 + jj * 16 + qd * 4 + r;
          Out[(size_t)row * E + cc] = (bf16_t)((acc[jj][n][r] + bvv) * sc);
        }
    }
  } else {
    // V -> VT sigma-permuted transpose: VT[(bh*64+d)*S + s0 + p],
    // inv_sigma: sl = a*16+b4*4+cc4 -> p = (a>>1)*32 + b4*8 + (a&1)*4 + cc4;
    // the 4 r-rows share (a,b4) -> one bf16x4 store.
#pragma unroll
    for (int n = 0; n < 4; ++n) {
      const int cc = ccb + wn * 64 + n * 16 + lq;
      const float bvv = bp[cc];
      const int d = cc & 63, hh = cc >> 6;
#pragma unroll
      for (int jj = 0; jj < 8; ++jj) {
        const int row = m0 + wm * 128 + jj * 16 + qd * 4;  // r=0 base
        const int bb_ = row >> 11;           // batch
        const int s_loc = row & (S - 1);
        const int sl = s_loc & 63, s0 = s_loc & ~63;
        const int a = sl >> 4, b4 = (sl >> 2) & 3;
        const int pb = (a >> 1) * 32 + b4 * 8 + (a & 1) * 4;
        bf16x4 vv;
#pragma unroll
        for (int r = 0; r < 4; ++r) vv[r] = (bf16_t)(acc[jj][n][r] + bvv);
        *(bf16x4*)&VT[((size_t)((bb_ * 16 + hh) * 64 + d)) * S + s0 + pb] = vv;
      }
    }
  }
}

// ---------------------------------------------------------------------------
// output projection: 64x128 tiles -> grid (8, 64) = 512 blocks.
// ---------------------------------------------------------------------------
__global__ __launch_bounds__(256) void oproj_gemm_kernel(
    const bf16_t* __restrict__ Ob, const bf16_t* __restrict__ wo,
    const float* __restrict__ bo, float* __restrict__ out) {
  __shared__ __align__(16) bf16_t As[64 * 64];    // 8 KB
  __shared__ __align__(16) bf16_t Bs[128 * 64];   // 16 KB
  const int tid = threadIdx.x;
  const int n0 = blockIdx.x * 128;
  const int m0 = blockIdx.y * 64;
  const int w = tid >> 6, l = tid & 63, lq = l & 15, qd = l >> 4;
  const int wr = (w >> 1) * 32, wc = (w & 1) * 64;

  f32x4 acc[2][4];
#pragma unroll
  for (int i = 0; i < 2; ++i)
#pragma unroll
    for (int j = 0; j < 4; ++j) acc[i][j] = (f32x4){0.f, 0.f, 0.f, 0.f};

  for (int kt = 0; kt < 16; ++kt) {
    __syncthreads();
    stage_tile<64, 256>(Ob + (size_t)m0 * E + kt * 64, E, As, tid);
    stage_tile<128, 256>(wo + (size_t)n0 * E + kt * 64, E, Bs, tid);
    __syncthreads();
#pragma unroll
    for (int ks = 0; ks < 2; ++ks) {
      bf16x8 af[2], bw[4];
#pragma unroll
      for (int mi = 0; mi < 2; ++mi)
        af[mi] = read_frag(As, wr + mi * 16 + lq, ks * 4 + qd);
#pragma unroll
      for (int ni = 0; ni < 4; ++ni)
        bw[ni] = read_frag(Bs, wc + ni * 16 + lq, ks * 4 + qd);
#pragma unroll
      for (int mi = 0; mi < 2; ++mi)
#pragma unroll
        for (int ni = 0; ni < 4; ++ni)
          acc[mi][ni] = MFMA16(af[mi], bw[ni], acc[mi][ni]);
    }
  }
#pragma unroll
  for (int ni = 0; ni < 4; ++ni) {
    const int col = n0 + wc + ni * 16 + lq;
    const float bvv = bo[col];
#pragma unroll
    for (int mi = 0; mi < 2; ++mi)
#pragma unroll
      for (int r = 0; r < 4; ++r) {
        const int row = m0 + wr + mi * 16 + qd * 4 + r;
        out[(size_t)row * E + col] = acc[mi][ni][r] + bvv;
      }
  }
}

// ---------------------------------------------------------------------------
// causal flash attention v13: operand-swapped S^T = K*Q^T (softmax'd regs ARE
// the PV A-fragment; keys sigma-permuted in VT; P never touches LDS).
//  * T15 PIPELINE: PV of tile kt-1 executes during iteration kt, overlapping
//    the softmax VALU of tile kt. V TRIPLE-buffered (40 KB LDS, 2 blocks/CU).
//  * ROW-SUM VIA MFMA: rs = P x ones; output layout row=qd*4+r is exactly
//    the O-write layout (no shuffles; error cancels with bf16-rounded P).
//  * __builtin_amdgcn_exp2f; setprio(1) around QK+PV MFMA cluster.
// Uniform work: block = q-tile pair {31-p, p} = 33 k-tiles. 512 blocks x
// 256 thr = 2 blocks/CU, 8 waves/CU sustained. No-max softmax (Q pre-scaled
// by log2e/8). XCD-clustered mapping: g=bid&7 -> bh in [4g,4g+4).
// ---------------------------------------------------------------------------
__global__ __launch_bounds__(256, 2) void attn_kernel(
    const bf16_t* __restrict__ Q, const bf16_t* __restrict__ K,
    const bf16_t* __restrict__ VT, bf16_t* __restrict__ O) {
  __shared__ __align__(16) bf16_t Ks[2][64 * 64];  // K dbuf, swizzled [key][d]
  __shared__ __align__(16) bf16_t Vt[3][64 * 64];  // V tri-buf, swizzled [d][perm-key]

  const int tid = threadIdx.x;
  const int w = tid >> 6, l = tid & 63;
  const int lq = l & 15, qd = l >> 4;
  const int bid = blockIdx.x;
  const int g = bid & 7, t = bid >> 3;  // 64 blocks per XCD-group
  const int bh = g * 4 + (t & 3);       // 4 bh per XCD-group: L2-resident K/VT
  const int p = t >> 2;                 // pair index: q-tiles {31-p, p}
  const int b = bh >> 4, h = bh & 15;
  const size_t rowbase = (size_t)b * S;
  const bf16_t* Kg = K + rowbase * E + h * 64;
  const bf16_t* Vg = VT + (size_t)bh * 64 * S;

  // constant all-ones B-fragment for the row-sum MFMA
  bf16x8 ones;
#pragma unroll
  for (int j = 0; j < 8; ++j) ones[j] = (bf16_t)1.0f;

  // prefetch k-tile 0 into K slot 0 / V slot 0
  stage_tile<64, 256>(Kg, E, Ks[0], tid);
  stage_tile<64, 256>(Vg, S, Vt[0], tid);
  int cb = 0;    // K slot of current tile
  int vcur = 0;  // V slot of current tile

#pragma unroll 1
  for (int seg = 0; seg < 2; ++seg) {
    const int qt = seg ? p : 31 - p;    // heavy q-tile first
    const int qr = qt * 64 + w * 16;    // wave rows [qr, qr+16)

    // Q fragments (pre-scaled), used as the MFMA B-operand: rows qr+lq
    bf16x8 aq[2];
#pragma unroll
    for (int ks = 0; ks < 2; ++ks)
      aq[ks] = *(const bf16x8*)(Q + (rowbase + qr + lq) * E + h * 64 +
                                ks * 32 + qd * 8);

    f32x4 oacc[4];
#pragma unroll
    for (int nt = 0; nt < 4; ++nt) oacc[nt] = (f32x4){0.f, 0.f, 0.f, 0.f};
    f32x4 osum = (f32x4){0.f, 0.f, 0.f, 0.f};  // row sums via ones-MFMA
    bf16x8 ap_prev[2];                          // P frags of tile kt-1
    int vprev = vcur;

    // PV of the previous tile from V slot vp (reads ap_prev; accumulates
    // oacc + osum). Issued right after QK so its MFMAs overlap softmax VALU.
    auto do_pv = [&](const bf16_t* Vp) {
#pragma unroll
      for (int ks = 0; ks < 2; ++ks) {
        bf16x8 bv[4];
#pragma unroll
        for (int nt = 0; nt < 4; ++nt)
          bv[nt] = read_frag(Vp, nt * 16 + lq, ks * 4 + qd);
#pragma unroll
        for (int nt = 0; nt < 4; ++nt)
          oacc[nt] = MFMA16(ap_prev[ks], bv[nt], oacc[nt]);
        osum = MFMA16(ap_prev[ks], ones, osum);
      }
    };

    for (int kt = 0; kt <= qt; ++kt) {
      __syncthreads();  // own vmcnt(0) drains DMA into K[cb]/V[vcur]; all
                        // waves' reads of the slots being rewritten are done
      const int vnext = (vcur + 1 == 3) ? 0 : vcur + 1;
      if (kt < qt) {    // stage tile kt+1
        const int kn = (kt + 1) * 64;
        stage_tile<64, 256>(Kg + (size_t)kn * E, E, Ks[cb ^ 1], tid);
        stage_tile<64, 256>(Vg + kn, S, Vt[vnext], tid);
      } else if (seg == 0) {  // last A-iter: prefetch segment B's tile 0
        stage_tile<64, 256>(Kg, E, Ks[cb ^ 1], tid);
        stage_tile<64, 256>(Vg, S, Vt[vnext], tid);
      }
      const bf16_t* Kc = Ks[cb];
      const int k0 = kt * 64;
      const bool needmask = (kt == qt);  // exact: kt<qt => k0+63 < qr

      // ---- S^T = K * Q^T : 8 MFMA; lane holds q=lq, keys nt*16+qd*4+r ----
      f32x4 sacc[4];
#pragma unroll
      for (int nt = 0; nt < 4; ++nt) sacc[nt] = (f32x4){0.f, 0.f, 0.f, 0.f};
      __builtin_amdgcn_s_setprio(1);
#pragma unroll
      for (int ks = 0; ks < 2; ++ks) {
        bf16x8 bk[4];
#pragma unroll
        for (int nt = 0; nt < 4; ++nt)
          bk[nt] = read_frag(Kc, nt * 16 + lq, ks * 4 + qd);
#pragma unroll
        for (int nt = 0; nt < 4; ++nt)
          sacc[nt] = MFMA16(bk[nt], aq[ks], sacc[nt]);
      }
      // ---- PV of tile kt-1 (independent of softmax below; overlaps it) ----
      if (kt > 0) do_pv(Vt[vprev]);
      __builtin_amdgcn_s_setprio(0);

      // ---- softmax in registers; pack directly into next PV A-frags ----
      // ap[ks][j] = pv(nt = ks*2 + (j>>2), r = j&3)  [matches VT's sigma]
#pragma unroll
      for (int nt = 0; nt < 4; ++nt)
#pragma unroll
        for (int r = 0; r < 4; ++r) {
          float pv = __builtin_amdgcn_exp2f(sacc[nt][r]);
          if (needmask) {
            const int kg = k0 + nt * 16 + qd * 4 + r;  // key index
            const int qg = qr + lq;                    // query index
            pv = (kg > qg) ? 0.f : pv;
          }
          ap_prev[nt >> 1][((nt & 1) << 2) | r] = (bf16_t)pv;
        }
      vprev = vcur;
      vcur = vnext;
      cb ^= 1;
    }
    // epilogue: PV of the segment's last tile
    do_pv(Vt[vprev]);

    // normalize + store: osum[r] = rs for q-row qd*4+r (all cols equal) --
    // exactly the C-layout rows this lane writes. No shuffles needed.
    float rinv[4];
#pragma unroll
    for (int r = 0; r < 4; ++r) rinv[r] = 1.0f / osum[r];
#pragma unroll
    for (int nt = 0; nt < 4; ++nt)
#pragma unroll
      for (int r = 0; r < 4; ++r) {
        const int qg = qr + qd * 4 + r;
        O[(rowbase + qg) * E + h * 64 + nt * 16 + lq] =
            (bf16_t)(oacc[nt][r] * rinv[r]);
      }
  }
}

// ---------------------------------------------------------------------------
// launch
// ---------------------------------------------------------------------------
extern "C" void kernel_launch(void* const* d_in, const int* in_sizes, int n_in,
                              void* d_out, int out_size, void* d_ws, size_t ws_size,
                              hipStream_t stream) {
  const float* x  = (const float*)d_in[0];
  const float* Wq = (const float*)d_in[1];
  const float* bq = (const float*)d_in[2];
  const float* Wk = (const float*)d_in[3];
  const float* bk = (const float*)d_in[4];
  const float* Wv = (const float*)d_in[5];
  const float* bv = (const float*)d_in[6];
  const float* Wo = (const float*)d_in[7];
  const float* bo = (const float*)d_in[8];
  float* out = (float*)d_out;

  unsigned char* ws = (unsigned char*)d_ws;
  constexpr size_t MB = 1ull << 20;
  bf16_t* xb  = (bf16_t*)(ws + 0 * MB);   // 8 MB; reused as Ob after qkv
  bf16_t* wqb = (bf16_t*)(ws + 8 * MB);   // wq/wk/wv contiguous [3072][1024]
  bf16_t* wkb = (bf16_t*)(ws + 10 * MB);
  bf16_t* wvb = (bf16_t*)(ws + 12 * MB);
  bf16_t* wob = (bf16_t*)(ws + 14 * MB);
  bf16_t* Qb  = (bf16_t*)(ws + 16 * MB);  // Q/K contiguous [2][4096][1024]
  bf16_t* VT  = (bf16_t*)(ws + 40 * MB);  // [32 bh][64 d][2048 s, sigma-perm per 64]
  bf16_t* Ob  = xb;                       // xb dead after qkv

  cvt_all_kernel<<<4096 + 4 * 1024, 256, 0, stream>>>(
      x, Wq, Wk, Wv, Wo, xb, wqb, wkb, wvb, wob);

  qkv8_kernel<<<192, 512, 0, stream>>>(xb, wqb, bq, bk, bv, Qb, VT);

  attn_kernel<<<512, 256, 0, stream>>>(Qb, Qb + (size_t)M * E, VT, Ob);

  oproj_gemm_kernel<<<dim3(8, 64), 256, 0, stream>>>(Ob, wob, bo, out);
}

// Round 6
// 173.810 us; speedup vs baseline: 1.2011x; 1.0016x over previous
//
#include <hip/hip_runtime.h>
#include <hip/hip_bf16.h>

typedef __bf16 bf16_t;
typedef __bf16 bf16x8 __attribute__((ext_vector_type(8)));
typedef __bf16 bf16x4 __attribute__((ext_vector_type(4)));
typedef float  f32x4  __attribute__((ext_vector_type(4)));

#define MFMA16(a, b, c) __builtin_amdgcn_mfma_f32_16x16x32_bf16((a), (b), (c), 0, 0, 0)

constexpr int E  = 1024;
constexpr int S  = 2048;
constexpr int H  = 16;
constexpr int M  = 4096;  // B*S

// ---------------------------------------------------------------------------
// async global->LDS 16B (wave-uniform LDS base + lane*16)
// ---------------------------------------------------------------------------
__device__ __forceinline__ void glds16(const bf16_t* src, bf16_t* dst) {
  __builtin_amdgcn_global_load_lds(
      (const __attribute__((address_space(1))) void*)src,
      (__attribute__((address_space(3))) void*)dst, 16, 0, 0);
}

// Stage a [ROWS x 64] bf16 tile (global row stride gld) into LDS, XOR-swizzled.
// NT = block threads.
template <int ROWS, int NT>
__device__ __forceinline__ void stage_tile(const bf16_t* g, int gld,
                                           bf16_t* lds, int tid) {
  const int w = tid >> 6, l = tid & 63;
#pragma unroll
  for (int i = 0; i < ROWS * 8 / NT; ++i) {
    const int c = i * NT + w * 64 + l;
    const int row = c >> 3;
    const int gch = (c & 7) ^ (row & 7);
    glds16(g + (size_t)row * gld + gch * 8, lds + (size_t)(i * NT + w * 64) * 8);
  }
}

// Stage a [64 x 128] bf16 tile (row stride gld) into LDS, XOR-swizzled in
// 16B chunks within each row (chunk' = chunk ^ (row&7), within 8-chunk halves).
// NT=256: 4 glds/thread.
__device__ __forceinline__ void stage_v128(const bf16_t* g, int gld,
                                           bf16_t* lds, int tid) {
#pragma unroll
  for (int i = 0; i < 4; ++i) {
    const int c = i * 256 + tid;          // [0,1024)
    const int row = c >> 4, col16 = c & 15;
    const int gch = col16 ^ (row & 7);
    glds16(g + (size_t)row * gld + gch * 8, lds + (size_t)c * 8);
  }
}

// Stage interleaved A-chunk c of a 256-row tile (qkv kernel helper).
__device__ __forceinline__ void stage_A_chunk(const bf16_t* g, int c,
                                              bf16_t* lds, int tid) {
  const int w = tid >> 6, l = tid & 63;
#pragma unroll
  for (int i = 0; i < 2; ++i) {
    const int gc = i * 512 + w * 64 + l;      // [0,1024)
    const int row_l = gc >> 3;                // [0,128)
    const int col8 = gc & 7;
    const int h = row_l >> 6, rr = row_l & 63;
    const int row = h * 128 + c * 64 + rr;    // LDS == global row
    const int gch = col8 ^ (row & 7);
    glds16(g + (size_t)row * E + gch * 8, lds + ((size_t)row * 8 + col8) * 8);
  }
}

// Read an 8-elem k-chunk (kc in [0,8)) of row `row` from a swizzled [R x 64] tile.
__device__ __forceinline__ bf16x8 read_frag(const bf16_t* lds, int row, int kc) {
  return *(const bf16x8*)(lds + (size_t)((row << 3) + (kc ^ (row & 7))) * 8);
}

// Read an 8-elem chunk (kc in [0,16)) of row `row` from a swizzled [64 x 128] tile.
__device__ __forceinline__ bf16x8 read_v128(const bf16_t* lds, int row, int kc) {
  return *(const bf16x8*)(lds + (size_t)((row << 4) + (kc ^ (row & 7))) * 8);
}

// ---------------------------------------------------------------------------
// fused fp32->bf16 conversion for x + 4 weight matrices
// ---------------------------------------------------------------------------
__global__ void cvt_all_kernel(const float* __restrict__ x,
                               const float* __restrict__ w0, const float* __restrict__ w1,
                               const float* __restrict__ w2, const float* __restrict__ w3,
                               bf16_t* __restrict__ xb,
                               bf16_t* __restrict__ o0, bf16_t* __restrict__ o1,
                               bf16_t* __restrict__ o2, bf16_t* __restrict__ o3) {
  const int bid = blockIdx.x;
  const float* s;
  bf16_t* d;
  int idx;
  if (bid < 4096) {
    s = x; d = xb; idx = bid * 256 + threadIdx.x;
  } else {
    const int seg = (bid - 4096) >> 10;
    s = seg == 0 ? w0 : seg == 1 ? w1 : seg == 2 ? w2 : w3;
    d = seg == 0 ? o0 : seg == 1 ? o1 : seg == 2 ? o2 : o3;
    idx = ((bid - 4096) & 1023) * 256 + threadIdx.x;
  }
  float4 v = ((const float4*)s)[idx];
  bf16x4 o;
  o[0] = (bf16_t)v.x; o[1] = (bf16_t)v.y; o[2] = (bf16_t)v.z; o[3] = (bf16_t)v.w;
  ((bf16x4*)d)[idx] = o;
}

// ---------------------------------------------------------------------------
// fused QKV projection, v4 (kept): m201-style 256x256 8-phase, counted vmcnt.
// Grid 192 (16m x 12n); W fused [3072][1024]; Q/K row-major; V -> sigma-VT.
// Q PRE-SCALED by log2(e)/8.
// ---------------------------------------------------------------------------
__global__ __launch_bounds__(512, 1) void qkv8_kernel(
    const bf16_t* __restrict__ xb, const bf16_t* __restrict__ W3,
    const float* __restrict__ bq, const float* __restrict__ bk,
    const float* __restrict__ bv, bf16_t* __restrict__ QKb,
    bf16_t* __restrict__ VT) {
  __shared__ __align__(16) bf16_t As[2][256 * 64];  // 64 KB
  __shared__ __align__(16) bf16_t Bs[2][256 * 64];  // 64 KB
  const int tid = threadIdx.x;
  const int l = tid & 63, lq = l & 15, qd = l >> 4;
  const int w = tid >> 6, wm = w >> 2, wn = w & 3;

  const int swz = (blockIdx.x & 7) * 24 + (blockIdx.x >> 3);
  const int by = swz / 12, bx = swz % 12;
  const int m0 = by * 256, n0 = bx * 256;

  const bf16_t* Ag = xb + (size_t)m0 * E;
  const bf16_t* Bg = W3 + (size_t)n0 * E;

  f32x4 acc[8][4];
#pragma unroll
  for (int jj = 0; jj < 8; ++jj)
#pragma unroll
    for (int n = 0; n < 4; ++n) acc[jj][n] = (f32x4){0.f, 0.f, 0.f, 0.f};

  stage_tile<128, 512>(Bg, E, Bs[0], tid);
  stage_tile<128, 512>(Bg + (size_t)128 * E, E, Bs[0] + 128 * 64, tid);
  stage_A_chunk(Ag, 0, As[0], tid);
  stage_A_chunk(Ag, 1, As[0], tid);
  asm volatile("s_waitcnt vmcnt(2)" ::: "memory");
  __builtin_amdgcn_s_barrier();

#pragma unroll 1
  for (int g = 0; g < 16; ++g) {
    const int s = g & 1;
    const bf16_t* Al = As[s];
    const bf16_t* Bl = Bs[s];
    bf16_t* An = As[s ^ 1];
    bf16_t* Bn = Bs[s ^ 1];
    const bf16_t* Agn = Ag + (g + 1) * 64;
    const bf16_t* Bgn = Bg + (g + 1) * 64;
    const bool more = (g < 15);
    bf16x8 af[4], bfr[4];

    // ph0: kk=0, jj 0-3 (+ all B kk0)
#pragma unroll
    for (int jj = 0; jj < 4; ++jj)
      af[jj] = read_frag(Al, wm * 128 + jj * 16 + lq, qd);
#pragma unroll
    for (int n = 0; n < 4; ++n)
      bfr[n] = read_frag(Bl, wn * 64 + n * 16 + lq, qd);
    if (more) stage_tile<128, 512>(Bgn, E, Bn, tid);
    __builtin_amdgcn_s_barrier();
    asm volatile("s_waitcnt lgkmcnt(0)" ::: "memory");
    __builtin_amdgcn_sched_barrier(0);
    __builtin_amdgcn_s_setprio(1);
#pragma unroll
    for (int jj = 0; jj < 4; ++jj)
#pragma unroll
      for (int n = 0; n < 4; ++n)
        acc[jj][n] = MFMA16(af[jj], bfr[n], acc[jj][n]);
    __builtin_amdgcn_s_setprio(0);
    if (more) asm volatile("s_waitcnt vmcnt(2)" ::: "memory");
    else      asm volatile("s_waitcnt vmcnt(0)" ::: "memory");
    __builtin_amdgcn_s_barrier();

    // ph1: kk=0, jj 4-7
#pragma unroll
    for (int jj = 0; jj < 4; ++jj)
      af[jj] = read_frag(Al, wm * 128 + (4 + jj) * 16 + lq, qd);
    if (more) stage_tile<128, 512>(Bgn + (size_t)128 * E, E, Bn + 128 * 64, tid);
    __builtin_amdgcn_s_barrier();
    asm volatile("s_waitcnt lgkmcnt(0)" ::: "memory");
    __builtin_amdgcn_sched_barrier(0);
    __builtin_amdgcn_s_setprio(1);
#pragma unroll
    for (int jj = 0; jj < 4; ++jj)
#pragma unroll
      for (int n = 0; n < 4; ++n)
        acc[4 + jj][n] = MFMA16(af[jj], bfr[n], acc[4 + jj][n]);
    __builtin_amdgcn_s_setprio(0);
    __builtin_amdgcn_s_barrier();

    // ph2: kk=1, jj 0-3 (+ all B kk1)
#pragma unroll
    for (int jj = 0; jj < 4; ++jj)
      af[jj] = read_frag(Al, wm * 128 + jj * 16 + lq, 4 + qd);
#pragma unroll
    for (int n = 0; n < 4; ++n)
      bfr[n] = read_frag(Bl, wn * 64 + n * 16 + lq, 4 + qd);
    if (more) stage_A_chunk(Agn, 0, An, tid);
    __builtin_amdgcn_s_barrier();
    asm volatile("s_waitcnt lgkmcnt(0)" ::: "memory");
    __builtin_amdgcn_sched_barrier(0);
    __builtin_amdgcn_s_setprio(1);
#pragma unroll
    for (int jj = 0; jj < 4; ++jj)
#pragma unroll
      for (int n = 0; n < 4; ++n)
        acc[jj][n] = MFMA16(af[jj], bfr[n], acc[jj][n]);
    __builtin_amdgcn_s_setprio(0);
    __builtin_amdgcn_s_barrier();

    // ph3: kk=1, jj 4-7
#pragma unroll
    for (int jj = 0; jj < 4; ++jj)
      af[jj] = read_frag(Al, wm * 128 + (4 + jj) * 16 + lq, 4 + qd);
    if (more) stage_A_chunk(Agn, 1, An, tid);
    __builtin_amdgcn_s_barrier();
    asm volatile("s_waitcnt lgkmcnt(0)" ::: "memory");
    __builtin_amdgcn_sched_barrier(0);
    __builtin_amdgcn_s_setprio(1);
#pragma unroll
    for (int jj = 0; jj < 4; ++jj)
#pragma unroll
      for (int n = 0; n < 4; ++n)
        acc[4 + jj][n] = MFMA16(af[jj], bfr[n], acc[4 + jj][n]);
    __builtin_amdgcn_s_setprio(0);
    if (more) asm volatile("s_waitcnt vmcnt(2)" ::: "memory");
    __builtin_amdgcn_s_barrier();
  }

  const int mat = n0 >> 10;            // 0=Q, 1=K, 2=V
  const int ccb = n0 & 1023;
  const float* bp = (mat == 0) ? bq : (mat == 1) ? bk : bv;
  if (mat < 2) {
    const float sc = (mat == 0) ? 0.18033688011112043f : 1.0f;  // log2(e)/8
    bf16_t* Out = QKb + (size_t)mat * ((size_t)M * E);
#pragma unroll
    for (int n = 0; n < 4; ++n) {
      const int cc = ccb + wn * 64 + n * 16 + lq;
      const float bvv = bp[cc];
#pragma unroll
      for (int jj = 0; jj < 8; ++jj)
#pragma unroll
        for (int r = 0; r < 4; ++r) {
          const int row = m0 + wm * 128 + jj * 16 + qd * 4 + r;
          Out[(size_t)row * E + cc] = (bf16_t)((acc[jj][n][r] + bvv) * sc);
        }
    }
  } else {
#pragma unroll
    for (int n = 0; n < 4; ++n) {
      const int cc = ccb + wn * 64 + n * 16 + lq;
      const float bvv = bp[cc];
      const int d = cc & 63, hh = cc >> 6;
#pragma unroll
      for (int jj = 0; jj < 8; ++jj) {
        const int row = m0 + wm * 128 + jj * 16 + qd * 4;  // r=0 base
        const int bb_ = row >> 11;           // batch
        const int s_loc = row & (S - 1);
        const int sl = s_loc & 63, s0 = s_loc & ~63;
        const int a = sl >> 4, b4 = (sl >> 2) & 3;
        const int pb = (a >> 1) * 32 + b4 * 8 + (a & 1) * 4;
        bf16x4 vv;
#pragma unroll
        for (int r = 0; r < 4; ++r) vv[r] = (bf16_t)(acc[jj][n][r] + bvv);
        *(bf16x4*)&VT[((size_t)((bb_ * 16 + hh) * 64 + d)) * S + s0 + pb] = vv;
      }
    }
  }
}

// ---------------------------------------------------------------------------
// output projection: 64x128 tiles -> grid (8, 64) = 512 blocks.
// ---------------------------------------------------------------------------
__global__ __launch_bounds__(256) void oproj_gemm_kernel(
    const bf16_t* __restrict__ Ob, const bf16_t* __restrict__ wo,
    const float* __restrict__ bo, float* __restrict__ out) {
  __shared__ __align__(16) bf16_t As[64 * 64];    // 8 KB
  __shared__ __align__(16) bf16_t Bs[128 * 64];   // 16 KB
  const int tid = threadIdx.x;
  const int n0 = blockIdx.x * 128;
  const int m0 = blockIdx.y * 64;
  const int w = tid >> 6, l = tid & 63, lq = l & 15, qd = l >> 4;
  const int wr = (w >> 1) * 32, wc = (w & 1) * 64;

  f32x4 acc[2][4];
#pragma unroll
  for (int i = 0; i < 2; ++i)
#pragma unroll
    for (int j = 0; j < 4; ++j) acc[i][j] = (f32x4){0.f, 0.f, 0.f, 0.f};

  for (int kt = 0; kt < 16; ++kt) {
    __syncthreads();
    stage_tile<64, 256>(Ob + (size_t)m0 * E + kt * 64, E, As, tid);
    stage_tile<128, 256>(wo + (size_t)n0 * E + kt * 64, E, Bs, tid);
    __syncthreads();
#pragma unroll
    for (int ks = 0; ks < 2; ++ks) {
      bf16x8 af[2], bw[4];
#pragma unroll
      for (int mi = 0; mi < 2; ++mi)
        af[mi] = read_frag(As, wr + mi * 16 + lq, ks * 4 + qd);
#pragma unroll
      for (int ni = 0; ni < 4; ++ni)
        bw[ni] = read_frag(Bs, wc + ni * 16 + lq, ks * 4 + qd);
#pragma unroll
      for (int mi = 0; mi < 2; ++mi)
#pragma unroll
        for (int ni = 0; ni < 4; ++ni)
          acc[mi][ni] = MFMA16(af[mi], bw[ni], acc[mi][ni]);
    }
  }
#pragma unroll
  for (int ni = 0; ni < 4; ++ni) {
    const int col = n0 + wc + ni * 16 + lq;
    const float bvv = bo[col];
#pragma unroll
    for (int mi = 0; mi < 2; ++mi)
#pragma unroll
      for (int r = 0; r < 4; ++r) {
        const int row = m0 + wr + mi * 16 + qd * 4 + r;
        out[(size_t)row * E + col] = acc[mi][ni][r] + bvv;
      }
  }
}

// ---------------------------------------------------------------------------
// causal flash attention v14: operand-swapped S^T = K*Q^T (softmax'd regs ARE
// the PV A-fragment; keys sigma-permuted in VT; P never touches LDS).
//
// v14 = v12's PROVEN geometry (4 waves x 16 q-rows, 512x256, uniform pairs,
// dbuf, VALU row-sum + shuffle epilogue; v13's tri-buffer/ones-MFMA/PV-delay
// REVERTED - R3 arithmetic showed v13 regressed ~3.4us) with:
//  * KVBLK=128: two 64-key tiles per barrier. Halves barriers (34->18),
//    staging transitions, and loop-state VALU. Uniform pairing survives:
//    T(qt)=ceil((qt+1)/2), TA+TB = 17 for every pair {31-p, p}. Mask still
//    confined to the single LAST tile of each segment (for qt odd the
//    previous tile ends at qt*64-65 < row-min; for qt even at qt*64-1).
//    qt even wastes the dead upper-64-key half of its last tile (~3%).
//  * __builtin_amdgcn_exp2f (single v_exp_f32), setprio around MFMA clusters.
// LDS 64 KB/block -> still 2 blocks/CU, 8 waves/CU flat.
// No-max softmax (Q pre-scaled by log2e/8); XCD map g=bid&7 -> bh [4g,4g+4).
// ---------------------------------------------------------------------------
__global__ __launch_bounds__(256, 2) void attn_kernel(
    const bf16_t* __restrict__ Q, const bf16_t* __restrict__ K,
    const bf16_t* __restrict__ VT, bf16_t* __restrict__ O) {
  __shared__ __align__(16) bf16_t Ks[2][128 * 64];  // dbuf swizzled [key][d], 32 KB
  __shared__ __align__(16) bf16_t Vt[2][64 * 128];  // dbuf swizzled [d][perm-key], 32 KB

  const int tid = threadIdx.x;
  const int w = tid >> 6, l = tid & 63;
  const int lq = l & 15, qd = l >> 4;
  const int bid = blockIdx.x;
  const int g = bid & 7, t = bid >> 3;  // 64 blocks per XCD-group
  const int bh = g * 4 + (t & 3);       // 4 bh per XCD-group: L2-resident K/VT
  const int p = t >> 2;                 // pair index: q-tiles {31-p, p}
  const int b = bh >> 4, h = bh & 15;
  const size_t rowbase = (size_t)b * S;
  const bf16_t* Kg = K + rowbase * E + h * 64;
  const bf16_t* Vg = VT + (size_t)bh * 64 * S;

  // prefetch 128-key tile 0 into buffer 0
  stage_tile<128, 256>(Kg, E, Ks[0], tid);
  stage_v128(Vg, S, Vt[0], tid);
  int cb = 0;

#pragma unroll 1
  for (int seg = 0; seg < 2; ++seg) {
    const int qt = seg ? p : 31 - p;    // heavy q-tile first
    const int T = (qt + 2) >> 1;        // 128-key tiles this segment
    const int qr = qt * 64 + w * 16;    // wave rows [qr, qr+16)
    const int qg = qr + lq;             // this lane's query row

    // Q fragments (pre-scaled), used as the MFMA B-operand: rows qr+lq
    bf16x8 aq[2];
#pragma unroll
    for (int ks = 0; ks < 2; ++ks)
      aq[ks] = *(const bf16x8*)(Q + (rowbase + qr + lq) * E + h * 64 +
                                ks * 32 + qd * 8);

    f32x4 oacc[4];
#pragma unroll
    for (int nt = 0; nt < 4; ++nt) oacc[nt] = (f32x4){0.f, 0.f, 0.f, 0.f};
    float rs4[4] = {0.f, 0.f, 0.f, 0.f};

    for (int kt = 0; kt < T; ++kt) {
      __syncthreads();  // own vmcnt(0) drains DMA into buffer cb; all waves'
                        // reads of buffer cb^1 (previous iter) are complete
      if (kt < T - 1) {           // stage tile kt+1 into the other buffer
        const int kn = (kt + 1) * 128;
        stage_tile<128, 256>(Kg + (size_t)kn * E, E, Ks[cb ^ 1], tid);
        stage_v128(Vg + kn, S, Vt[cb ^ 1], tid);
      } else if (seg == 0) {      // last A-iter: prefetch segment B's tile 0
        stage_tile<128, 256>(Kg, E, Ks[cb ^ 1], tid);
        stage_v128(Vg, S, Vt[cb ^ 1], tid);
      }
      const bf16_t* Kc = Ks[cb];
      const bf16_t* Vc = Vt[cb];
      const int k0 = kt * 128;
      const bool needmask = (kt == T - 1);

      // ---- S^T = K * Q^T : 16 MFMA; lane holds q=lq, keys nt*16+qd*4+r ----
      f32x4 sacc[8];
#pragma unroll
      for (int nt = 0; nt < 8; ++nt) sacc[nt] = (f32x4){0.f, 0.f, 0.f, 0.f};
      __builtin_amdgcn_s_setprio(1);
#pragma unroll
      for (int ks = 0; ks < 2; ++ks) {
        bf16x8 bk[8];
#pragma unroll
        for (int nt = 0; nt < 8; ++nt)
          bk[nt] = read_frag(Kc, nt * 16 + lq, ks * 4 + qd);
#pragma unroll
        for (int nt = 0; nt < 8; ++nt)
          sacc[nt] = MFMA16(bk[nt], aq[ks], sacc[nt]);
      }
      __builtin_amdgcn_s_setprio(0);

      // ---- softmax in registers; pack directly into PV A-frags ----
      // ap[c][j] = pv(nt = c*2 + (j>>2), r = j&3)  [matches VT's sigma
      // within each 64-key block; c = ks-chunk of 32 keys]
      bf16x8 ap[4];
      if (needmask) {
#pragma unroll
        for (int nt = 0; nt < 8; ++nt)
#pragma unroll
          for (int r = 0; r < 4; ++r) {
            float pv = __builtin_amdgcn_exp2f(sacc[nt][r]);
            const int kg = k0 + nt * 16 + qd * 4 + r;  // key index
            pv = (kg > qg) ? 0.f : pv;
            rs4[nt & 3] += pv;
            ap[nt >> 1][((nt & 1) << 2) | r] = (bf16_t)pv;
          }
      } else {
#pragma unroll
        for (int nt = 0; nt < 8; ++nt)
#pragma unroll
          for (int r = 0; r < 4; ++r) {
            float pv = __builtin_amdgcn_exp2f(sacc[nt][r]);
            rs4[nt & 3] += pv;
            ap[nt >> 1][((nt & 1) << 2) | r] = (bf16_t)pv;
          }
      }

      // ---- O += P * V : 16 MFMA ----
      __builtin_amdgcn_s_setprio(1);
#pragma unroll
      for (int c = 0; c < 4; ++c) {
        bf16x8 bv[4];
#pragma unroll
        for (int nt = 0; nt < 4; ++nt)
          bv[nt] = read_v128(Vc, nt * 16 + lq, c * 4 + qd);
#pragma unroll
        for (int nt = 0; nt < 4; ++nt)
          oacc[nt] = MFMA16(ap[c], bv[nt], oacc[nt]);
      }
      __builtin_amdgcn_s_setprio(0);
      cb ^= 1;
    }

    // row-sum totals: lane's rs is the partial for q-row lq over its qd's
    // keys; xor-16/32 sums the 4 qd groups. Then redistribute for the
    // C-layout write (lane needs rows qd*4+r, held by lanes lq = qd*4+r).
    float rs = (rs4[0] + rs4[1]) + (rs4[2] + rs4[3]);
    rs += __shfl_xor(rs, 16);
    rs += __shfl_xor(rs, 32);
    float rinv[4];
#pragma unroll
    for (int r = 0; r < 4; ++r) rinv[r] = 1.0f / __shfl(rs, qd * 4 + r);
#pragma unroll
    for (int nt = 0; nt < 4; ++nt)
#pragma unroll
      for (int r = 0; r < 4; ++r) {
        const int qgw = qr + qd * 4 + r;
        O[(rowbase + qgw) * E + h * 64 + nt * 16 + lq] =
            (bf16_t)(oacc[nt][r] * rinv[r]);
      }
  }
}

// ---------------------------------------------------------------------------
// launch
// ---------------------------------------------------------------------------
extern "C" void kernel_launch(void* const* d_in, const int* in_sizes, int n_in,
                              void* d_out, int out_size, void* d_ws, size_t ws_size,
                              hipStream_t stream) {
  const float* x  = (const float*)d_in[0];
  const float* Wq = (const float*)d_in[1];
  const float* bq = (const float*)d_in[2];
  const float* Wk = (const float*)d_in[3];
  const float* bk = (const float*)d_in[4];
  const float* Wv = (const float*)d_in[5];
  const float* bv = (const float*)d_in[6];
  const float* Wo = (const float*)d_in[7];
  const float* bo = (const float*)d_in[8];
  float* out = (float*)d_out;

  unsigned char* ws = (unsigned char*)d_ws;
  constexpr size_t MB = 1ull << 20;
  bf16_t* xb  = (bf16_t*)(ws + 0 * MB);   // 8 MB; reused as Ob after qkv
  bf16_t* wqb = (bf16_t*)(ws + 8 * MB);   // wq/wk/wv contiguous [3072][1024]
  bf16_t* wkb = (bf16_t*)(ws + 10 * MB);
  bf16_t* wvb = (bf16_t*)(ws + 12 * MB);
  bf16_t* wob = (bf16_t*)(ws + 14 * MB);
  bf16_t* Qb  = (bf16_t*)(ws + 16 * MB);  // Q/K contiguous [2][4096][1024]
  bf16_t* VT  = (bf16_t*)(ws + 40 * MB);  // [32 bh][64 d][2048 s, sigma-perm per 64]
  bf16_t* Ob  = xb;                       // xb dead after qkv

  cvt_all_kernel<<<4096 + 4 * 1024, 256, 0, stream>>>(
      x, Wq, Wk, Wv, Wo, xb, wqb, wkb, wvb, wob);

  qkv8_kernel<<<192, 512, 0, stream>>>(xb, wqb, bq, bk, bv, Qb, VT);

  attn_kernel<<<512, 256, 0, stream>>>(Qb, Qb + (size_t)M * E, VT, Ob);

  oproj_gemm_kernel<<<dim3(8, 64), 256, 0, stream>>>(Ob, wob, bo, out);
}

// Round 7
// 171.795 us; speedup vs baseline: 1.2152x; 1.0117x over previous
//
#include <hip/hip_runtime.h>
#include <hip/hip_bf16.h>

typedef __bf16 bf16_t;
typedef __bf16 bf16x8 __attribute__((ext_vector_type(8)));
typedef __bf16 bf16x4 __attribute__((ext_vector_type(4)));
typedef float  f32x4  __attribute__((ext_vector_type(4)));

#define MFMA16(a, b, c) __builtin_amdgcn_mfma_f32_16x16x32_bf16((a), (b), (c), 0, 0, 0)

constexpr int E  = 1024;
constexpr int S  = 2048;
constexpr int H  = 16;
constexpr int M  = 4096;  // B*S

// ---------------------------------------------------------------------------
// async global->LDS 16B (wave-uniform LDS base + lane*16)
// ---------------------------------------------------------------------------
__device__ __forceinline__ void glds16(const bf16_t* src, bf16_t* dst) {
  __builtin_amdgcn_global_load_lds(
      (const __attribute__((address_space(1))) void*)src,
      (__attribute__((address_space(3))) void*)dst, 16, 0, 0);
}

// Stage a [ROWS x 64] bf16 tile (global row stride gld) into LDS, XOR-swizzled.
// NT = block threads.
template <int ROWS, int NT>
__device__ __forceinline__ void stage_tile(const bf16_t* g, int gld,
                                           bf16_t* lds, int tid) {
  const int w = tid >> 6, l = tid & 63;
#pragma unroll
  for (int i = 0; i < ROWS * 8 / NT; ++i) {
    const int c = i * NT + w * 64 + l;
    const int row = c >> 3;
    const int gch = (c & 7) ^ (row & 7);
    glds16(g + (size_t)row * gld + gch * 8, lds + (size_t)(i * NT + w * 64) * 8);
  }
}

// Stage a [64 x 128] bf16 tile (row stride gld) into LDS, XOR-swizzled in
// 16B chunks within each row. NT=256: 4 glds/thread.
__device__ __forceinline__ void stage_v128(const bf16_t* g, int gld,
                                           bf16_t* lds, int tid) {
#pragma unroll
  for (int i = 0; i < 4; ++i) {
    const int c = i * 256 + tid;          // [0,1024)
    const int row = c >> 4, col16 = c & 15;
    const int gch = col16 ^ (row & 7);
    glds16(g + (size_t)row * gld + gch * 8, lds + (size_t)c * 8);
  }
}

// Stage interleaved A-chunk c of a 256-row tile: LDS rows
// {h*128 + c*64 + rr : h in {0,1}, rr in [0,64)} (2 glds/thread @512 thr).
__device__ __forceinline__ void stage_A_chunk(const bf16_t* g, int c,
                                              bf16_t* lds, int tid) {
  const int w = tid >> 6, l = tid & 63;
#pragma unroll
  for (int i = 0; i < 2; ++i) {
    const int gc = i * 512 + w * 64 + l;      // [0,1024)
    const int row_l = gc >> 3;                // [0,128)
    const int col8 = gc & 7;
    const int h = row_l >> 6, rr = row_l & 63;
    const int row = h * 128 + c * 64 + rr;    // LDS == global row
    const int gch = col8 ^ (row & 7);
    glds16(g + (size_t)row * E + gch * 8, lds + ((size_t)row * 8 + col8) * 8);
  }
}

// Read an 8-elem k-chunk (kc in [0,8)) of row `row` from a swizzled [R x 64] tile.
__device__ __forceinline__ bf16x8 read_frag(const bf16_t* lds, int row, int kc) {
  return *(const bf16x8*)(lds + (size_t)((row << 3) + (kc ^ (row & 7))) * 8);
}

// Read an 8-elem chunk (kc in [0,16)) of row `row` from a swizzled [64 x 128] tile.
__device__ __forceinline__ bf16x8 read_v128(const bf16_t* lds, int row, int kc) {
  return *(const bf16x8*)(lds + (size_t)((row << 4) + (kc ^ (row & 7))) * 8);
}

// ---------------------------------------------------------------------------
// fused fp32->bf16 conversion for x + 4 weight matrices
// ---------------------------------------------------------------------------
__global__ void cvt_all_kernel(const float* __restrict__ x,
                               const float* __restrict__ w0, const float* __restrict__ w1,
                               const float* __restrict__ w2, const float* __restrict__ w3,
                               bf16_t* __restrict__ xb,
                               bf16_t* __restrict__ o0, bf16_t* __restrict__ o1,
                               bf16_t* __restrict__ o2, bf16_t* __restrict__ o3) {
  const int bid = blockIdx.x;
  const float* s;
  bf16_t* d;
  int idx;
  if (bid < 4096) {
    s = x; d = xb; idx = bid * 256 + threadIdx.x;
  } else {
    const int seg = (bid - 4096) >> 10;
    s = seg == 0 ? w0 : seg == 1 ? w1 : seg == 2 ? w2 : w3;
    d = seg == 0 ? o0 : seg == 1 ? o1 : seg == 2 ? o2 : o3;
    idx = ((bid - 4096) & 1023) * 256 + threadIdx.x;
  }
  float4 v = ((const float4*)s)[idx];
  bf16x4 o;
  o[0] = (bf16_t)v.x; o[1] = (bf16_t)v.y; o[2] = (bf16_t)v.z; o[3] = (bf16_t)v.w;
  ((bf16x4*)d)[idx] = o;
}

// ---------------------------------------------------------------------------
// fused QKV projection, v5: v4's counted-vmcnt 4-phase schedule at 256x192
// -> grid 16x16 = 256 blocks = ALL CUs busy (v4 used 192 = 75%).
// 512 thr = 8 waves (2M x 4N), wave tile 128x48, acc 8x3.
// LDS 112 KB: As[2][256x64] + Bs[2][192x64], XOR-swizzled.
// Staging chunks per K-tile: B = 3 x 64-row (1 glds/thr), A = 2 interleaved
// (2 glds/thr). Issue: ph0->B0, ph1->B1, ph2->B2+A0, ph3->A1.
// Gates (counted, never 0 mid-loop):
//   end-ph0: vmcnt(1)  -> A1(t) landed for ph1 (B0(t+1) may fly)
//   end-ph3: vmcnt(2)  -> B0,B1,B2,A0 of t+1 landed (A1(t+1) may fly)
// Per-column epilogue routing (192-col tiles can span Q/K/V); V -> sigma-VT.
// Q PRE-SCALED by log2(e)/8.
// ---------------------------------------------------------------------------
__global__ __launch_bounds__(512, 1) void qkv8_kernel(
    const bf16_t* __restrict__ xb, const bf16_t* __restrict__ W3,
    const float* __restrict__ bq, const float* __restrict__ bk,
    const float* __restrict__ bv, bf16_t* __restrict__ QKb,
    bf16_t* __restrict__ VT) {
  __shared__ __align__(16) bf16_t As[2][256 * 64];  // 64 KB
  __shared__ __align__(16) bf16_t Bs[2][192 * 64];  // 48 KB
  const int tid = threadIdx.x;
  const int l = tid & 63, lq = l & 15, qd = l >> 4;
  const int w = tid >> 6, wm = w >> 2, wn = w & 3;

  // XCD-aware 4x4-region swizzle over the 16x16 block grid
  const int wg = blockIdx.x;
  const int xcd = wg & 7, i5 = wg >> 3;        // i5 in [0,32)
  const int region = xcd * 2 + (i5 >> 4);      // [0,16)
  const int j = i5 & 15;
  const int bx = (region & 3) * 4 + (j & 3);   // n-tile [0,16)
  const int by = (region >> 2) * 4 + (j >> 2); // m-tile [0,16)
  const int m0 = by * 256, n0 = bx * 192;

  const bf16_t* Ag = xb + (size_t)m0 * E;
  const bf16_t* Bg = W3 + (size_t)n0 * E;

  f32x4 acc[8][3];
#pragma unroll
  for (int jj = 0; jj < 8; ++jj)
#pragma unroll
    for (int n = 0; n < 3; ++n) acc[jj][n] = (f32x4){0.f, 0.f, 0.f, 0.f};

  // prologue: B0,B1,B2,A0,A1 of tile 0 (steady-state issue order)
  stage_tile<64, 512>(Bg, E, Bs[0], tid);
  stage_tile<64, 512>(Bg + (size_t)64 * E, E, Bs[0] + 64 * 64, tid);
  stage_tile<64, 512>(Bg + (size_t)128 * E, E, Bs[0] + 128 * 64, tid);
  stage_A_chunk(Ag, 0, As[0], tid);
  stage_A_chunk(Ag, 1, As[0], tid);
  asm volatile("s_waitcnt vmcnt(2)" ::: "memory");
  __builtin_amdgcn_s_barrier();

#pragma unroll 1
  for (int g = 0; g < 16; ++g) {
    const int s = g & 1;
    const bf16_t* Al = As[s];
    const bf16_t* Bl = Bs[s];
    bf16_t* An = As[s ^ 1];
    bf16_t* Bn = Bs[s ^ 1];
    const bf16_t* Agn = Ag + (g + 1) * 64;
    const bf16_t* Bgn = Bg + (g + 1) * 64;
    const bool more = (g < 15);
    bf16x8 af[4], bfr[3];

    // ph0: A jj0-3 kk0 + B kk0; stage B0(t+1)
#pragma unroll
    for (int jj = 0; jj < 4; ++jj)
      af[jj] = read_frag(Al, wm * 128 + jj * 16 + lq, qd);
#pragma unroll
    for (int n = 0; n < 3; ++n)
      bfr[n] = read_frag(Bl, wn * 48 + n * 16 + lq, qd);
    if (more) stage_tile<64, 512>(Bgn, E, Bn, tid);
    __builtin_amdgcn_s_barrier();
    asm volatile("s_waitcnt lgkmcnt(0)" ::: "memory");
    __builtin_amdgcn_sched_barrier(0);
    __builtin_amdgcn_s_setprio(1);
#pragma unroll
    for (int jj = 0; jj < 4; ++jj)
#pragma unroll
      for (int n = 0; n < 3; ++n)
        acc[jj][n] = MFMA16(af[jj], bfr[n], acc[jj][n]);
    __builtin_amdgcn_s_setprio(0);
    if (more) asm volatile("s_waitcnt vmcnt(1)" ::: "memory");
    else      asm volatile("s_waitcnt vmcnt(0)" ::: "memory");
    __builtin_amdgcn_s_barrier();

    // ph1: A jj4-7 kk0 (reuse B kk0 frags); stage B1(t+1)
#pragma unroll
    for (int jj = 0; jj < 4; ++jj)
      af[jj] = read_frag(Al, wm * 128 + (4 + jj) * 16 + lq, qd);
    if (more) stage_tile<64, 512>(Bgn + (size_t)64 * E, E, Bn + 64 * 64, tid);
    __builtin_amdgcn_s_barrier();
    asm volatile("s_waitcnt lgkmcnt(0)" ::: "memory");
    __builtin_amdgcn_sched_barrier(0);
    __builtin_amdgcn_s_setprio(1);
#pragma unroll
    for (int jj = 0; jj < 4; ++jj)
#pragma unroll
      for (int n = 0; n < 3; ++n)
        acc[4 + jj][n] = MFMA16(af[jj], bfr[n], acc[4 + jj][n]);
    __builtin_amdgcn_s_setprio(0);
    __builtin_amdgcn_s_barrier();

    // ph2: A jj0-3 kk1 + B kk1; stage B2(t+1) + A0(t+1)
#pragma unroll
    for (int jj = 0; jj < 4; ++jj)
      af[jj] = read_frag(Al, wm * 128 + jj * 16 + lq, 4 + qd);
#pragma unroll
    for (int n = 0; n < 3; ++n)
      bfr[n] = read_frag(Bl, wn * 48 + n * 16 + lq, 4 + qd);
    if (more) {
      stage_tile<64, 512>(Bgn + (size_t)128 * E, E, Bn + 128 * 64, tid);
      stage_A_chunk(Agn, 0, An, tid);
    }
    __builtin_amdgcn_s_barrier();
    asm volatile("s_waitcnt lgkmcnt(0)" ::: "memory");
    __builtin_amdgcn_sched_barrier(0);
    __builtin_amdgcn_s_setprio(1);
#pragma unroll
    for (int jj = 0; jj < 4; ++jj)
#pragma unroll
      for (int n = 0; n < 3; ++n)
        acc[jj][n] = MFMA16(af[jj], bfr[n], acc[jj][n]);
    __builtin_amdgcn_s_setprio(0);
    __builtin_amdgcn_s_barrier();

    // ph3: A jj4-7 kk1; stage A1(t+1)
#pragma unroll
    for (int jj = 0; jj < 4; ++jj)
      af[jj] = read_frag(Al, wm * 128 + (4 + jj) * 16 + lq, 4 + qd);
    if (more) stage_A_chunk(Agn, 1, An, tid);
    __builtin_amdgcn_s_barrier();
    asm volatile("s_waitcnt lgkmcnt(0)" ::: "memory");
    __builtin_amdgcn_sched_barrier(0);
    __builtin_amdgcn_s_setprio(1);
#pragma unroll
    for (int jj = 0; jj < 4; ++jj)
#pragma unroll
      for (int n = 0; n < 3; ++n)
        acc[4 + jj][n] = MFMA16(af[jj], bfr[n], acc[4 + jj][n]);
    __builtin_amdgcn_s_setprio(0);
    if (more) asm volatile("s_waitcnt vmcnt(2)" ::: "memory");
    __builtin_amdgcn_s_barrier();
  }

  // epilogue: per-column routing (192-col tile may span Q/K/V)
#pragma unroll
  for (int n = 0; n < 3; ++n) {
    const int col = n0 + wn * 48 + n * 16 + lq;
    const int mat = col >> 10, cc = col & 1023;
    const float bvv = (mat == 0 ? bq : mat == 1 ? bk : bv)[cc];
    if (mat < 2) {
      const float sc = (mat == 0) ? 0.18033688011112043f : 1.0f;  // log2(e)/8
      bf16_t* Out = QKb + (size_t)mat * ((size_t)M * E);
#pragma unroll
      for (int jj = 0; jj < 8; ++jj)
#pragma unroll
        for (int r = 0; r < 4; ++r) {
          const int row = m0 + wm * 128 + jj * 16 + qd * 4 + r;
          Out[(size_t)row * E + cc] = (bf16_t)((acc[jj][n][r] + bvv) * sc);
        }
    } else {
      // V -> VT sigma-permuted transpose; 4 r-rows -> one bf16x4 store
      const int d = cc & 63, hh = cc >> 6;
#pragma unroll
      for (int jj = 0; jj < 8; ++jj) {
        const int row = m0 + wm * 128 + jj * 16 + qd * 4;  // r=0 base
        const int bb_ = row >> 11;           // batch
        const int s_loc = row & (S - 1);
        const int sl = s_loc & 63, s0 = s_loc & ~63;
        const int a = sl >> 4, b4 = (sl >> 2) & 3;
        const int pb = (a >> 1) * 32 + b4 * 8 + (a & 1) * 4;
        bf16x4 vv;
#pragma unroll
        for (int r = 0; r < 4; ++r) vv[r] = (bf16_t)(acc[jj][n][r] + bvv);
        *(bf16x4*)&VT[((size_t)((bb_ * 16 + hh) * 64 + d)) * S + s0 + pb] = vv;
      }
    }
  }
}

// ---------------------------------------------------------------------------
// output projection: 64x128 tiles -> grid (8, 64) = 512 blocks.
// ---------------------------------------------------------------------------
__global__ __launch_bounds__(256) void oproj_gemm_kernel(
    const bf16_t* __restrict__ Ob, const bf16_t* __restrict__ wo,
    const float* __restrict__ bo, float* __restrict__ out) {
  __shared__ __align__(16) bf16_t As[64 * 64];    // 8 KB
  __shared__ __align__(16) bf16_t Bs[128 * 64];   // 16 KB
  const int tid = threadIdx.x;
  const int n0 = blockIdx.x * 128;
  const int m0 = blockIdx.y * 64;
  const int w = tid >> 6, l = tid & 63, lq = l & 15, qd = l >> 4;
  const int wr = (w >> 1) * 32, wc = (w & 1) * 64;

  f32x4 acc[2][4];
#pragma unroll
  for (int i = 0; i < 2; ++i)
#pragma unroll
    for (int j = 0; j < 4; ++j) acc[i][j] = (f32x4){0.f, 0.f, 0.f, 0.f};

  for (int kt = 0; kt < 16; ++kt) {
    __syncthreads();
    stage_tile<64, 256>(Ob + (size_t)m0 * E + kt * 64, E, As, tid);
    stage_tile<128, 256>(wo + (size_t)n0 * E + kt * 64, E, Bs, tid);
    __syncthreads();
#pragma unroll
    for (int ks = 0; ks < 2; ++ks) {
      bf16x8 af[2], bw[4];
#pragma unroll
      for (int mi = 0; mi < 2; ++mi)
        af[mi] = read_frag(As, wr + mi * 16 + lq, ks * 4 + qd);
#pragma unroll
      for (int ni = 0; ni < 4; ++ni)
        bw[ni] = read_frag(Bs, wc + ni * 16 + lq, ks * 4 + qd);
#pragma unroll
      for (int mi = 0; mi < 2; ++mi)
#pragma unroll
        for (int ni = 0; ni < 4; ++ni)
          acc[mi][ni] = MFMA16(af[mi], bw[ni], acc[mi][ni]);
    }
  }
#pragma unroll
  for (int ni = 0; ni < 4; ++ni) {
    const int col = n0 + wc + ni * 16 + lq;
    const float bvv = bo[col];
#pragma unroll
    for (int mi = 0; mi < 2; ++mi)
#pragma unroll
      for (int r = 0; r < 4; ++r) {
        const int row = m0 + wr + mi * 16 + qd * 4 + r;
        out[(size_t)row * E + col] = acc[mi][ni][r] + bvv;
      }
  }
}

// ---------------------------------------------------------------------------
// causal flash attention v15: operand-swapped S^T = K*Q^T; keys sigma-permuted
// in VT; P never touches LDS.  v15 = v14's KVBLK=128 + v13's overlap bundle:
//  * PV(kt-1) issued between QK(kt) and softmax(kt): softmax VALU overlaps
//    PV on the MFMA pipe. V TRIPLE-buffered; K dbuf. LDS 80 KB = exactly
//    2 blocks/CU (160 KB).
//  * ROW-SUM VIA ones-MFMA: osum[r] = rowsum for row qd*4+r = O-write layout
//    (no shuffles; kills 32 VALU adds/tile).
//  * KVBLK=128: T(qt)=ceil((qt+1)/2); TA+TB = 17 tiles for every pair
//    {31-p, p}; mask confined to each segment's last tile.
// Uniform work, 512 blocks x 256 thr, 8 waves/CU flat. No-max softmax
// (Q pre-scaled by log2e/8). XCD map g=bid&7 -> bh [4g,4g+4).
// ---------------------------------------------------------------------------
__global__ __launch_bounds__(256, 2) void attn_kernel(
    const bf16_t* __restrict__ Q, const bf16_t* __restrict__ K,
    const bf16_t* __restrict__ VT, bf16_t* __restrict__ O) {
  __shared__ __align__(16) bf16_t Ks[2][128 * 64];  // K dbuf, 32 KB
  __shared__ __align__(16) bf16_t Vt[3][64 * 128];  // V tri-buf, 48 KB

  const int tid = threadIdx.x;
  const int w = tid >> 6, l = tid & 63;
  const int lq = l & 15, qd = l >> 4;
  const int bid = blockIdx.x;
  const int g = bid & 7, t = bid >> 3;  // 64 blocks per XCD-group
  const int bh = g * 4 + (t & 3);       // 4 bh per XCD-group: L2-resident K/VT
  const int p = t >> 2;                 // pair index: q-tiles {31-p, p}
  const int b = bh >> 4, h = bh & 15;
  const size_t rowbase = (size_t)b * S;
  const bf16_t* Kg = K + rowbase * E + h * 64;
  const bf16_t* Vg = VT + (size_t)bh * 64 * S;

  bf16x8 ones;
#pragma unroll
  for (int jj = 0; jj < 8; ++jj) ones[jj] = (bf16_t)1.0f;

  // prefetch 128-key tile 0 into K slot 0 / V slot 0
  stage_tile<128, 256>(Kg, E, Ks[0], tid);
  stage_v128(Vg, S, Vt[0], tid);
  int cb = 0, vcur = 0;

#pragma unroll 1
  for (int seg = 0; seg < 2; ++seg) {
    const int qt = seg ? p : 31 - p;    // heavy q-tile first
    const int T = (qt + 2) >> 1;        // 128-key tiles this segment
    const int qr = qt * 64 + w * 16;    // wave rows [qr, qr+16)
    const int qg = qr + lq;             // this lane's query row

    bf16x8 aq[2];
#pragma unroll
    for (int ks = 0; ks < 2; ++ks)
      aq[ks] = *(const bf16x8*)(Q + (rowbase + qr + lq) * E + h * 64 +
                                ks * 32 + qd * 8);

    f32x4 oacc[4];
#pragma unroll
    for (int nt = 0; nt < 4; ++nt) oacc[nt] = (f32x4){0.f, 0.f, 0.f, 0.f};
    f32x4 osum = (f32x4){0.f, 0.f, 0.f, 0.f};
    bf16x8 ap_prev[4];                   // P frags of tile kt-1 (128 keys)
    int vprev = vcur;

    // PV of the previous tile: 16 oacc-MFMA + 4 ones-MFMA
    auto do_pv = [&](const bf16_t* Vp) {
#pragma unroll
      for (int c = 0; c < 4; ++c) {
        bf16x8 bv[4];
#pragma unroll
        for (int nt = 0; nt < 4; ++nt)
          bv[nt] = read_v128(Vp, nt * 16 + lq, c * 4 + qd);
#pragma unroll
        for (int nt = 0; nt < 4; ++nt)
          oacc[nt] = MFMA16(ap_prev[c], bv[nt], oacc[nt]);
        osum = MFMA16(ap_prev[c], ones, osum);
      }
    };

    for (int kt = 0; kt < T; ++kt) {
      __syncthreads();  // drains DMA into K[cb]/V[vcur]; all waves' reads of
                        // the slots being rewritten completed last iteration
      const int vnext = (vcur + 1 == 3) ? 0 : vcur + 1;
      if (kt < T - 1) {
        const int kn = (kt + 1) * 128;
        stage_tile<128, 256>(Kg + (size_t)kn * E, E, Ks[cb ^ 1], tid);
        stage_v128(Vg + kn, S, Vt[vnext], tid);
      } else if (seg == 0) {      // last A-iter: prefetch segment B's tile 0
        stage_tile<128, 256>(Kg, E, Ks[cb ^ 1], tid);
        stage_v128(Vg, S, Vt[vnext], tid);
      }
      const bf16_t* Kc = Ks[cb];
      const int k0 = kt * 128;
      const bool needmask = (kt == T - 1);

      // ---- S^T = K * Q^T : 16 MFMA; lane holds q=lq, keys nt*16+qd*4+r ----
      f32x4 sacc[8];
#pragma unroll
      for (int nt = 0; nt < 8; ++nt) sacc[nt] = (f32x4){0.f, 0.f, 0.f, 0.f};
      __builtin_amdgcn_s_setprio(1);
#pragma unroll
      for (int ks = 0; ks < 2; ++ks) {
        bf16x8 bk[8];
#pragma unroll
        for (int nt = 0; nt < 8; ++nt)
          bk[nt] = read_frag(Kc, nt * 16 + lq, ks * 4 + qd);
#pragma unroll
        for (int nt = 0; nt < 8; ++nt)
          sacc[nt] = MFMA16(bk[nt], aq[ks], sacc[nt]);
      }
      // ---- PV of tile kt-1 (independent; overlaps softmax below) ----
      if (kt > 0) do_pv(Vt[vprev]);
      __builtin_amdgcn_s_setprio(0);

      // ---- softmax in registers; pack into PV A-frags (VT sigma layout) ----
      if (needmask) {
#pragma unroll
        for (int nt = 0; nt < 8; ++nt)
#pragma unroll
          for (int r = 0; r < 4; ++r) {
            float pv = __builtin_amdgcn_exp2f(sacc[nt][r]);
            const int kg = k0 + nt * 16 + qd * 4 + r;
            pv = (kg > qg) ? 0.f : pv;
            ap_prev[nt >> 1][((nt & 1) << 2) | r] = (bf16_t)pv;
          }
      } else {
#pragma unroll
        for (int nt = 0; nt < 8; ++nt)
#pragma unroll
          for (int r = 0; r < 4; ++r) {
            float pv = __builtin_amdgcn_exp2f(sacc[nt][r]);
            ap_prev[nt >> 1][((nt & 1) << 2) | r] = (bf16_t)pv;
          }
      }
      vprev = vcur;
      vcur = vnext;
      cb ^= 1;
    }
    // epilogue: PV of the segment's last tile
    do_pv(Vt[vprev]);

    // normalize + store: osum[r] = rowsum for q-row qd*4+r = C-layout rows
    float rinv[4];
#pragma unroll
    for (int r = 0; r < 4; ++r) rinv[r] = 1.0f / osum[r];
#pragma unroll
    for (int nt = 0; nt < 4; ++nt)
#pragma unroll
      for (int r = 0; r < 4; ++r) {
        const int qgw = qr + qd * 4 + r;
        O[(rowbase + qgw) * E + h * 64 + nt * 16 + lq] =
            (bf16_t)(oacc[nt][r] * rinv[r]);
      }
  }
}

// ---------------------------------------------------------------------------
// launch
// ---------------------------------------------------------------------------
extern "C" void kernel_launch(void* const* d_in, const int* in_sizes, int n_in,
                              void* d_out, int out_size, void* d_ws, size_t ws_size,
                              hipStream_t stream) {
  const float* x  = (const float*)d_in[0];
  const float* Wq = (const float*)d_in[1];
  const float* bq = (const float*)d_in[2];
  const float* Wk = (const float*)d_in[3];
  const float* bk = (const float*)d_in[4];
  const float* Wv = (const float*)d_in[5];
  const float* bv = (const float*)d_in[6];
  const float* Wo = (const float*)d_in[7];
  const float* bo = (const float*)d_in[8];
  float* out = (float*)d_out;

  unsigned char* ws = (unsigned char*)d_ws;
  constexpr size_t MB = 1ull << 20;
  bf16_t* xb  = (bf16_t*)(ws + 0 * MB);   // 8 MB; reused as Ob after qkv
  bf16_t* wqb = (bf16_t*)(ws + 8 * MB);   // wq/wk/wv contiguous [3072][1024]
  bf16_t* wkb = (bf16_t*)(ws + 10 * MB);
  bf16_t* wvb = (bf16_t*)(ws + 12 * MB);
  bf16_t* wob = (bf16_t*)(ws + 14 * MB);
  bf16_t* Qb  = (bf16_t*)(ws + 16 * MB);  // Q/K contiguous [2][4096][1024]
  bf16_t* VT  = (bf16_t*)(ws + 40 * MB);  // [32 bh][64 d][2048 s, sigma-perm per 64]
  bf16_t* Ob  = xb;                       // xb dead after qkv

  cvt_all_kernel<<<4096 + 4 * 1024, 256, 0, stream>>>(
      x, Wq, Wk, Wv, Wo, xb, wqb, wkb, wvb, wob);

  qkv8_kernel<<<256, 512, 0, stream>>>(xb, wqb, bq, bk, bv, Qb, VT);

  attn_kernel<<<512, 256, 0, stream>>>(Qb, Qb + (size_t)M * E, VT, Ob);

  oproj_gemm_kernel<<<dim3(8, 64), 256, 0, stream>>>(Ob, wob, bo, out);
}